// Round 3
// baseline (193.598 us; speedup 1.0000x reference)
//
#include <hip/hip_runtime.h>
#include <hip/hip_bf16.h>

#define NHEADS 12
#define NFRAMES 8
#define NTOK 1568
#define CDIM 768
#define DHEAD 64
#define BATCH 2
#define MROWS (BATCH * NTOK) /* 3136 */
#define MPAD 3200
#define K3 (3 * CDIM)        /* 2304 */
#define AREA1 197
#define EXT1 228
#define TPF 196

typedef __bf16 bf16x8 __attribute__((ext_vector_type(8)));
typedef float f32x4 __attribute__((ext_vector_type(4)));
typedef float f32x16 __attribute__((ext_vector_type(16)));
typedef unsigned short u16x8 __attribute__((ext_vector_type(8)));

__device__ __forceinline__ unsigned short f2bf(float f) {
  return __builtin_bit_cast(unsigned short, (__bf16)f);
}
__device__ __forceinline__ float bf2f(unsigned short u) {
  unsigned int x = ((unsigned int)u) << 16;
  return __builtin_bit_cast(float, x);
}
__device__ __forceinline__ bf16x8 ld8(const unsigned short* p) {
  return __builtin_bit_cast(bf16x8, *(const u16x8*)p);
}
__device__ __forceinline__ f32x4 mfma16(bf16x8 a, bf16x8 b, f32x4 c) {
  return __builtin_amdgcn_mfma_f32_16x16x32_bf16(a, b, c, 0, 0, 0);
}
__device__ __forceinline__ f32x16 mfma32(bf16x8 a, bf16x8 b, f32x16 c) {
  return __builtin_amdgcn_mfma_f32_32x32x16_bf16(a, b, c, 0, 0, 0);
}
__device__ __forceinline__ unsigned int pack2(float lo, float hi) {
  return ((unsigned int)f2bf(hi) << 16) | (unsigned int)f2bf(lo);
}

// ---------------- conversion / packing ----------------
__global__ void conv_kernel(const float* __restrict__ x,
                            const float* __restrict__ qkv_w,
                            const float* __restrict__ proj_w,
                            unsigned short* __restrict__ xb,
                            unsigned short* __restrict__ qkvwb,
                            unsigned short* __restrict__ projwb,
                            unsigned short* __restrict__ aout) {
  const int XCH = MPAD * CDIM / 4;
  const int WCH = K3 * CDIM / 4;
  const int PCH = CDIM * CDIM / 4;
  const int ACH = (MPAD - MROWS) * CDIM / 4;
  const int total = XCH + WCH + PCH + ACH;
  for (int c = blockIdx.x * blockDim.x + threadIdx.x; c < total;
       c += gridDim.x * blockDim.x) {
    if (c < XCH) {
      int m = (c * 4) / CDIM;
      float4 v = make_float4(0.f, 0.f, 0.f, 0.f);
      if (m < MROWS) v = ((const float4*)x)[c];
      ushort4 o;
      o.x = f2bf(v.x); o.y = f2bf(v.y); o.z = f2bf(v.z); o.w = f2bf(v.w);
      ((ushort4*)xb)[c] = o;
    } else if (c < XCH + WCH) {
      int c2 = c - XCH;
      float4 v = ((const float4*)qkv_w)[c2];
      ushort4 o;
      o.x = f2bf(v.x); o.y = f2bf(v.y); o.z = f2bf(v.z); o.w = f2bf(v.w);
      ((ushort4*)qkvwb)[c2] = o;
    } else if (c < XCH + WCH + PCH) {
      int c2 = c - XCH - WCH;
      float4 v = ((const float4*)proj_w)[c2];
      ushort4 o;
      o.x = f2bf(v.x); o.y = f2bf(v.y); o.z = f2bf(v.z); o.w = f2bf(v.w);
      ((ushort4*)projwb)[c2] = o;
    } else {
      int c2 = c - XCH - WCH - PCH;
      ushort4 z; z.x = 0; z.y = 0; z.z = 0; z.w = 0;
      ((ushort4*)(aout + (size_t)MROWS * CDIM))[c2] = z;
    }
  }
}

// ---------------- bias table pre-gather ----------------
// bias1T[h][j=km_ext<228][i=qmod_ext<228] (bf16); bias2[h][qframe][kframe] (fp32).
__global__ void bias_kernel(const float* __restrict__ rpt,
                            const float* __restrict__ rtt,
                            const int* __restrict__ rpi,
                            const int* __restrict__ rti,
                            unsigned short* __restrict__ bias1T,
                            float* __restrict__ bias2) {
  int t = blockIdx.x * blockDim.x + threadIdx.x;
  const int n1 = NHEADS * EXT1 * EXT1;
  if (t < n1) {
    int h = t / (EXT1 * EXT1);
    int rem = t - h * (EXT1 * EXT1);
    int j = rem / EXT1;
    int i = rem - j * EXT1;
    int jm = (j >= AREA1) ? j - AREA1 : j;
    int im = (i >= AREA1) ? i - AREA1 : i;
    bias1T[t] = f2bf(rpt[rpi[im * AREA1 + jm] * NHEADS + h]);
  } else if (t < n1 + NHEADS * 64) {
    int t2 = t - n1;
    int h = t2 >> 6, ff = t2 & 63;
    bias2[t2] = rtt[rti[ff] * NHEADS + h];
  }
}

// ---------------- 128x128 MFMA GEMM (NT: both A,B row-major over K) ----------------
template <int MODE>
__global__ __launch_bounds__(256) void gemm_kernel(
    const unsigned short* __restrict__ A,
    const unsigned short* __restrict__ Bw,
    const float* __restrict__ bias0,   // q_bias (MODE0) / proj_b (MODE1)
    const float* __restrict__ biasv,   // v_bias (MODE0)
    unsigned short* __restrict__ qbuf,
    unsigned short* __restrict__ kbuf,
    unsigned short* __restrict__ vtbuf,
    float* __restrict__ Cout) {
  __shared__ unsigned short As[2][128 * 32];
  __shared__ unsigned short Bs[2][128 * 32];
  const int lane = threadIdx.x & 63;
  const int wv = threadIdx.x >> 6;
  const int m0 = blockIdx.y * 128;
  const int n0 = blockIdx.x * 128;

  auto stage = [&](int buf, int kt) {
    const int k0 = kt * 32;
#pragma unroll
    for (int issue = 0; issue < 2; ++issue) {
      const int c = issue * 256 + wv * 64 + lane;
      const int r = c >> 2;
      const int seg = c & 3;
      const unsigned short* ga = A + (size_t)(m0 + r) * CDIM + k0 + seg * 8;
      const unsigned short* gb = Bw + (size_t)(n0 + r) * CDIM + k0 + seg * 8;
      __builtin_amdgcn_global_load_lds(
          (const __attribute__((address_space(1))) void*)ga,
          (__attribute__((address_space(3))) void*)&As[buf][(issue * 256 + wv * 64) * 8],
          16, 0, 0);
      __builtin_amdgcn_global_load_lds(
          (const __attribute__((address_space(1))) void*)gb,
          (__attribute__((address_space(3))) void*)&Bs[buf][(issue * 256 + wv * 64) * 8],
          16, 0, 0);
    }
  };

  f32x4 acc[4][4] = {};
  const int rbase = (wv >> 1) * 64;
  const int cbase = (wv & 1) * 64;

  stage(0, 0);
  __syncthreads();
  int cur = 0;
  for (int kt = 0; kt < CDIM / 32; ++kt) {
    if (kt + 1 < CDIM / 32) stage(cur ^ 1, kt + 1);
    bf16x8 af[4], bg[4];
#pragma unroll
    for (int i = 0; i < 4; ++i) {
      af[i] = ld8(&As[cur][(rbase + i * 16 + (lane & 15)) * 32 + (lane >> 4) * 8]);
      bg[i] = ld8(&Bs[cur][(cbase + i * 16 + (lane & 15)) * 32 + (lane >> 4) * 8]);
    }
#pragma unroll
    for (int i = 0; i < 4; ++i)
#pragma unroll
      for (int j = 0; j < 4; ++j)
        acc[i][j] = mfma16(af[i], bg[j], acc[i][j]);
    __syncthreads();
    cur ^= 1;
  }

#pragma unroll
  for (int i = 0; i < 4; ++i) {
#pragma unroll
    for (int j = 0; j < 4; ++j) {
#pragma unroll
      for (int r = 0; r < 4; ++r) {
        int grow = m0 + rbase + i * 16 + (lane >> 4) * 4 + r;
        int gcol = n0 + cbase + j * 16 + (lane & 15);
        if (grow >= MROWS) continue;
        float v = acc[i][j][r];
        if (MODE == 0) {
          int which = gcol / CDIM;
          int cc = gcol - which * CDIM;
          int hh = cc >> 6, dd = cc & 63;
          int b = grow / NTOK, n = grow - b * NTOK;
          size_t hd = ((size_t)(b * NHEADS + hh) * NTOK + n) * 64 + dd;
          if (which == 0)
            qbuf[hd] = f2bf((v + bias0[cc]) * 0.125f);
          else if (which == 1)
            kbuf[hd] = f2bf(v);
          else
            vtbuf[((size_t)(b * NHEADS + hh) * 64 + dd) * NTOK + n] =
                f2bf(v + biasv[cc]);
        } else {
          Cout[(size_t)grow * CDIM + gcol] = v + bias0[gcol];
        }
      }
    }
  }
}

// ---------------- flash attention v3: split-KV x4, swapped QK^T, 32x32 MFMA ----------
// 1176 blocks (one per bh x q-tile), 4 waves each own k-tiles kt = wv, wv+4, ...
// XCD-swizzled blockIdx (1176 = 8*147). LDS merge of (m,l,O) partials.
__global__ __launch_bounds__(256, 4) void attn_kernel(
    const unsigned short* __restrict__ qbuf,
    const unsigned short* __restrict__ kbuf,
    const unsigned short* __restrict__ vtbuf,
    const unsigned short* __restrict__ bias1T,
    const float* __restrict__ bias2,
    unsigned short* __restrict__ aout) {
  __shared__ float olds[4][64][36];  // pad 36: 16B-aligned rows, minimal bank aliasing
  __shared__ float mlds[4][64];
  __shared__ float llds[4][64];
  const int lane = threadIdx.x & 63;
  const int wv = threadIdx.x >> 6;
  const int wu = (blockIdx.x & 7) * 147 + (blockIdx.x >> 3);  // 0..1175
  const int bh = wu / 49;
  const int qt = wu - bh * 49;
  const int q0 = qt * 32;
  const int h = bh % NHEADS;
  const int b = bh / NHEADS;
  const int qlane = lane & 31;
  const int hi = lane >> 5;
  const int qn = q0 + qlane;
  const int qfr = qn / TPF;

  const unsigned short* qp = qbuf + (size_t)bh * NTOK * DHEAD;
  const unsigned short* kp = kbuf + (size_t)bh * NTOK * DHEAD;
  const unsigned short* vp = vtbuf + (size_t)bh * DHEAD * NTOK;
  const unsigned short* b1 = bias1T + (size_t)h * EXT1 * EXT1 + (q0 % AREA1) + qlane;
  const float* b2p = bias2 + h * 64 + qfr * 8;

  bf16x8 aq[4];
#pragma unroll
  for (int c = 0; c < 4; ++c)
    aq[c] = ld8(qp + (size_t)qn * DHEAD + c * 16 + hi * 8);

  f32x16 o0 = {}, o1 = {};
  float mrun = -1.0e30f, lrun = 0.f;

  bf16x8 kf[4];
#pragma unroll
  for (int c = 0; c < 4; ++c)
    kf[c] = ld8(kp + (size_t)(wv * 32 + qlane) * DHEAD + c * 16 + hi * 8);

  int base = wv * 32;  // kv0 % 197 for this wave's tile sequence
  for (int kt = wv; kt < NTOK / 32; kt += 4) {
    const int kv0 = kt * 32;
    f32x16 s = {};
#pragma unroll
    for (int c = 0; c < 4; ++c) s = mfma32(kf[c], aq[c], s);
    if (kt + 4 < NTOK / 32) {
#pragma unroll
      for (int c = 0; c < 4; ++c)
        kf[c] = ld8(kp + (size_t)(kv0 + 128 + qlane) * DHEAD + c * 16 + hi * 8);
    }
    bf16x8 vf0 = ld8(vp + (size_t)qlane * NTOK + kv0 + hi * 8);
    bf16x8 vf1 = ld8(vp + (size_t)qlane * NTOK + kv0 + 16 + hi * 8);
    bf16x8 vf2 = ld8(vp + (size_t)(32 + qlane) * NTOK + kv0 + hi * 8);
    bf16x8 vf3 = ld8(vp + (size_t)(32 + qlane) * NTOK + kv0 + 16 + hi * 8);

    const int kfl = kv0 / TPF;
    const int bnd = (kfl + 1) * TPF;
    const float b2lo = b2p[kfl];
    const float b2hi = b2p[kfl < 7 ? kfl + 1 : 7];
#pragma unroll
    for (int r = 0; r < 16; ++r) {
      const int kit = (r & 3) + 8 * (r >> 2) + 4 * hi;
      s[r] += bf2f(b1[(size_t)(base + kit) * EXT1]) +
              ((kv0 + kit) >= bnd ? b2hi : b2lo);
    }

    float tmax = s[0];
#pragma unroll
    for (int r = 1; r < 16; ++r) tmax = fmaxf(tmax, s[r]);
    tmax = fmaxf(tmax, __shfl_xor(tmax, 32));
    if (!__all(tmax - mrun <= 8.0f)) {  // T13 defer-max
      const float mnew = fmaxf(mrun, tmax);
      const float fac = __expf(mrun - mnew);
      lrun *= fac;
#pragma unroll
      for (int r = 0; r < 16; ++r) { o0[r] *= fac; o1[r] *= fac; }
      mrun = mnew;
    }
#pragma unroll
    for (int r = 0; r < 16; ++r) s[r] = __expf(s[r] - mrun);
    float ps = 0.f;
#pragma unroll
    for (int r = 0; r < 16; ++r) ps += s[r];
    ps += __shfl_xor(ps, 32);
    lrun += ps;

    unsigned int dw[8], e[8];
#pragma unroll
    for (int c = 0; c < 8; ++c) dw[c] = pack2(s[2 * c], s[2 * c + 1]);
#pragma unroll
    for (int c = 0; c < 8; ++c) e[c] = __shfl_xor(dw[c], 32);
    unsigned int f0[4], f1[4];
    f0[0] = hi ? e[2] : dw[0];  f0[1] = hi ? e[3] : dw[1];
    f0[2] = hi ? dw[2] : e[0];  f0[3] = hi ? dw[3] : e[1];
    f1[0] = hi ? e[6] : dw[4];  f1[1] = hi ? e[7] : dw[5];
    f1[2] = hi ? dw[6] : e[4];  f1[3] = hi ? dw[7] : e[5];
    const bf16x8 F0 = __builtin_bit_cast(bf16x8, *(ulonglong2*)f0);
    const bf16x8 F1 = __builtin_bit_cast(bf16x8, *(ulonglong2*)f1);

    o0 = mfma32(vf0, F0, o0);
    o0 = mfma32(vf1, F1, o0);
    o1 = mfma32(vf2, F0, o1);
    o1 = mfma32(vf3, F1, o1);

    base += 128;
    if (base >= AREA1) base -= AREA1;
  }

  // ---- merge partials across the 4 waves ----
  mlds[wv][lane] = mrun;
  llds[wv][lane] = lrun;
#pragma unroll
  for (int r = 0; r < 16; ++r) {
    olds[wv][lane][r] = o0[r];
    olds[wv][lane][16 + r] = o1[r];
  }
  __syncthreads();

  float msv[4];
#pragma unroll
  for (int s4 = 0; s4 < 4; ++s4) msv[s4] = mlds[s4][lane];
  float M = fmaxf(fmaxf(msv[0], msv[1]), fmaxf(msv[2], msv[3]));
  float wgt[4], L = 0.f;
#pragma unroll
  for (int s4 = 0; s4 < 4; ++s4) {
    wgt[s4] = __expf(msv[s4] - M);
    L += llds[s4][lane] * wgt[s4];
  }
  const float rinv = 1.0f / L;
  unsigned short* op = aout + (size_t)(b * NTOK + qn) * CDIM + h * 64;
#pragma unroll
  for (int gi = 0; gi < 2; ++gi) {
    const int g = wv * 2 + gi;
    float acc[4] = {0.f, 0.f, 0.f, 0.f};
#pragma unroll
    for (int s4 = 0; s4 < 4; ++s4) {
#pragma unroll
      for (int j = 0; j < 4; ++j)
        acc[j] += olds[s4][lane][4 * g + j] * wgt[s4];
    }
    const int dbase = (g < 4 ? 8 * g : 32 + 8 * (g - 4)) + 4 * hi;
    *(unsigned int*)(op + dbase) = pack2(acc[0] * rinv, acc[1] * rinv);
    *(unsigned int*)(op + dbase + 2) = pack2(acc[2] * rinv, acc[3] * rinv);
  }
}

extern "C" void kernel_launch(void* const* d_in, const int* in_sizes, int n_in,
                              void* d_out, int out_size, void* d_ws, size_t ws_size,
                              hipStream_t stream) {
  (void)in_sizes; (void)n_in; (void)out_size; (void)ws_size;
  const float* x        = (const float*)d_in[0];
  const float* qkv_w    = (const float*)d_in[1];
  const float* q_bias   = (const float*)d_in[2];
  const float* v_bias   = (const float*)d_in[3];
  const float* rp_table = (const float*)d_in[4];
  const float* rt_table = (const float*)d_in[5];
  const float* proj_w   = (const float*)d_in[6];
  const float* proj_b   = (const float*)d_in[7];
  const int* rp_index   = (const int*)d_in[8];
  const int* rt_index   = (const int*)d_in[9];

  char* ws = (char*)d_ws;
  unsigned short* xb     = (unsigned short*)(ws);
  unsigned short* qkvwb  = (unsigned short*)(ws + 4915200);
  unsigned short* projwb = (unsigned short*)(ws + 8454144);
  unsigned short* qbuf   = (unsigned short*)(ws + 9633792);
  unsigned short* kbuf   = (unsigned short*)(ws + 14450688);
  unsigned short* vtbuf  = (unsigned short*)(ws + 19267584);
  unsigned short* aout   = (unsigned short*)(ws + 24084480);
  unsigned short* bias1T = (unsigned short*)(ws + 28999680);
  float* bias2           = (float*)(ws + 30247424);  // was 30246816: overlapped bias1T tail (race)

  conv_kernel<<<2048, 256, 0, stream>>>(x, qkv_w, proj_w, xb, qkvwb, projwb, aout);
  bias_kernel<<<(NHEADS * EXT1 * EXT1 + NHEADS * 64 + 255) / 256, 256, 0, stream>>>(
      rp_table, rt_table, rp_index, rt_index, bias1T, bias2);
  gemm_kernel<0><<<dim3(K3 / 128, MPAD / 128), 256, 0, stream>>>(
      xb, qkvwb, q_bias, v_bias, qbuf, kbuf, vtbuf, nullptr);
  attn_kernel<<<dim3(1176), 256, 0, stream>>>(
      qbuf, kbuf, vtbuf, bias1T, bias2, aout);
  gemm_kernel<1><<<dim3(CDIM / 128, MPAD / 128), 256, 0, stream>>>(
      aout, projwb, proj_b, nullptr, nullptr, nullptr, nullptr, (float*)d_out);
}

// Round 4
// 158.319 us; speedup vs baseline: 1.2228x; 1.2228x over previous
//
#include <hip/hip_runtime.h>
#include <hip/hip_bf16.h>

#define NHEADS 12
#define NFRAMES 8
#define NTOK 1568
#define CDIM 768
#define DHEAD 64
#define BATCH 2
#define MROWS (BATCH * NTOK) /* 3136 */
#define MPAD 3200
#define K3 (3 * CDIM)        /* 2304 */
#define AREA1 197
#define EXT1 228
#define TPF 196

typedef __bf16 bf16x8 __attribute__((ext_vector_type(8)));
typedef float f32x4 __attribute__((ext_vector_type(4)));
typedef float f32x16 __attribute__((ext_vector_type(16)));
typedef unsigned short u16x8 __attribute__((ext_vector_type(8)));

__device__ __forceinline__ unsigned short f2bf(float f) {
  return __builtin_bit_cast(unsigned short, (__bf16)f);
}
__device__ __forceinline__ float bf2f(unsigned short u) {
  unsigned int x = ((unsigned int)u) << 16;
  return __builtin_bit_cast(float, x);
}
__device__ __forceinline__ bf16x8 ld8(const unsigned short* p) {
  return __builtin_bit_cast(bf16x8, *(const u16x8*)p);
}
__device__ __forceinline__ f32x4 mfma16(bf16x8 a, bf16x8 b, f32x4 c) {
  return __builtin_amdgcn_mfma_f32_16x16x32_bf16(a, b, c, 0, 0, 0);
}
__device__ __forceinline__ f32x16 mfma32(bf16x8 a, bf16x8 b, f32x16 c) {
  return __builtin_amdgcn_mfma_f32_32x32x16_bf16(a, b, c, 0, 0, 0);
}
__device__ __forceinline__ unsigned int pack2(float lo, float hi) {
  return ((unsigned int)f2bf(hi) << 16) | (unsigned int)f2bf(lo);
}

// ---------------- conversion / packing ----------------
__global__ void conv_kernel(const float* __restrict__ x,
                            const float* __restrict__ qkv_w,
                            const float* __restrict__ proj_w,
                            unsigned short* __restrict__ xb,
                            unsigned short* __restrict__ qkvwb,
                            unsigned short* __restrict__ projwb,
                            unsigned short* __restrict__ aout) {
  const int XCH = MPAD * CDIM / 4;
  const int WCH = K3 * CDIM / 4;
  const int PCH = CDIM * CDIM / 4;
  const int ACH = (MPAD - MROWS) * CDIM / 4;
  const int total = XCH + WCH + PCH + ACH;
  for (int c = blockIdx.x * blockDim.x + threadIdx.x; c < total;
       c += gridDim.x * blockDim.x) {
    if (c < XCH) {
      int m = (c * 4) / CDIM;
      float4 v = make_float4(0.f, 0.f, 0.f, 0.f);
      if (m < MROWS) v = ((const float4*)x)[c];
      ushort4 o;
      o.x = f2bf(v.x); o.y = f2bf(v.y); o.z = f2bf(v.z); o.w = f2bf(v.w);
      ((ushort4*)xb)[c] = o;
    } else if (c < XCH + WCH) {
      int c2 = c - XCH;
      float4 v = ((const float4*)qkv_w)[c2];
      ushort4 o;
      o.x = f2bf(v.x); o.y = f2bf(v.y); o.z = f2bf(v.z); o.w = f2bf(v.w);
      ((ushort4*)qkvwb)[c2] = o;
    } else if (c < XCH + WCH + PCH) {
      int c2 = c - XCH - WCH;
      float4 v = ((const float4*)proj_w)[c2];
      ushort4 o;
      o.x = f2bf(v.x); o.y = f2bf(v.y); o.z = f2bf(v.z); o.w = f2bf(v.w);
      ((ushort4*)projwb)[c2] = o;
    } else {
      int c2 = c - XCH - WCH - PCH;
      ushort4 z; z.x = 0; z.y = 0; z.z = 0; z.w = 0;
      ((ushort4*)(aout + (size_t)MROWS * CDIM))[c2] = z;
    }
  }
}

// ---------------- bias table pre-gather ----------------
// bias1T[h][j=km_ext<228][i=qmod_ext<228] (bf16); bias2[h][qframe][kframe] (fp32).
__global__ void bias_kernel(const float* __restrict__ rpt,
                            const float* __restrict__ rtt,
                            const int* __restrict__ rpi,
                            const int* __restrict__ rti,
                            unsigned short* __restrict__ bias1T,
                            float* __restrict__ bias2) {
  int t = blockIdx.x * blockDim.x + threadIdx.x;
  const int n1 = NHEADS * EXT1 * EXT1;
  if (t < n1) {
    int h = t / (EXT1 * EXT1);
    int rem = t - h * (EXT1 * EXT1);
    int j = rem / EXT1;
    int i = rem - j * EXT1;
    int jm = (j >= AREA1) ? j - AREA1 : j;
    int im = (i >= AREA1) ? i - AREA1 : i;
    bias1T[t] = f2bf(rpt[rpi[im * AREA1 + jm] * NHEADS + h]);
  } else if (t < n1 + NHEADS * 64) {
    int t2 = t - n1;
    int h = t2 >> 6, ff = t2 & 63;
    bias2[t2] = rtt[rti[ff] * NHEADS + h];
  }
}

// ---------------- 128x128 MFMA GEMM (NT: both A,B row-major over K) ----------------
template <int MODE>
__global__ __launch_bounds__(256) void gemm_kernel(
    const unsigned short* __restrict__ A,
    const unsigned short* __restrict__ Bw,
    const float* __restrict__ bias0,   // q_bias (MODE0) / proj_b (MODE1)
    const float* __restrict__ biasv,   // v_bias (MODE0)
    unsigned short* __restrict__ qbuf,
    unsigned short* __restrict__ kbuf,
    unsigned short* __restrict__ vtbuf,
    float* __restrict__ Cout) {
  __shared__ unsigned short As[2][128 * 32];
  __shared__ unsigned short Bs[2][128 * 32];
  const int lane = threadIdx.x & 63;
  const int wv = threadIdx.x >> 6;
  const int m0 = blockIdx.y * 128;
  const int n0 = blockIdx.x * 128;

  auto stage = [&](int buf, int kt) {
    const int k0 = kt * 32;
#pragma unroll
    for (int issue = 0; issue < 2; ++issue) {
      const int c = issue * 256 + wv * 64 + lane;
      const int r = c >> 2;
      const int seg = c & 3;
      const unsigned short* ga = A + (size_t)(m0 + r) * CDIM + k0 + seg * 8;
      const unsigned short* gb = Bw + (size_t)(n0 + r) * CDIM + k0 + seg * 8;
      __builtin_amdgcn_global_load_lds(
          (const __attribute__((address_space(1))) void*)ga,
          (__attribute__((address_space(3))) void*)&As[buf][(issue * 256 + wv * 64) * 8],
          16, 0, 0);
      __builtin_amdgcn_global_load_lds(
          (const __attribute__((address_space(1))) void*)gb,
          (__attribute__((address_space(3))) void*)&Bs[buf][(issue * 256 + wv * 64) * 8],
          16, 0, 0);
    }
  };

  f32x4 acc[4][4] = {};
  const int rbase = (wv >> 1) * 64;
  const int cbase = (wv & 1) * 64;

  stage(0, 0);
  __syncthreads();
  int cur = 0;
  for (int kt = 0; kt < CDIM / 32; ++kt) {
    if (kt + 1 < CDIM / 32) stage(cur ^ 1, kt + 1);
    bf16x8 af[4], bg[4];
#pragma unroll
    for (int i = 0; i < 4; ++i) {
      af[i] = ld8(&As[cur][(rbase + i * 16 + (lane & 15)) * 32 + (lane >> 4) * 8]);
      bg[i] = ld8(&Bs[cur][(cbase + i * 16 + (lane & 15)) * 32 + (lane >> 4) * 8]);
    }
#pragma unroll
    for (int i = 0; i < 4; ++i)
#pragma unroll
      for (int j = 0; j < 4; ++j)
        acc[i][j] = mfma16(af[i], bg[j], acc[i][j]);
    __syncthreads();
    cur ^= 1;
  }

#pragma unroll
  for (int i = 0; i < 4; ++i) {
#pragma unroll
    for (int j = 0; j < 4; ++j) {
#pragma unroll
      for (int r = 0; r < 4; ++r) {
        int grow = m0 + rbase + i * 16 + (lane >> 4) * 4 + r;
        int gcol = n0 + cbase + j * 16 + (lane & 15);
        if (grow >= MROWS) continue;
        float v = acc[i][j][r];
        if (MODE == 0) {
          int which = gcol / CDIM;
          int cc = gcol - which * CDIM;
          int hh = cc >> 6, dd = cc & 63;
          int b = grow / NTOK, n = grow - b * NTOK;
          size_t hd = ((size_t)(b * NHEADS + hh) * NTOK + n) * 64 + dd;
          if (which == 0)
            qbuf[hd] = f2bf((v + bias0[cc]) * 0.125f);
          else if (which == 1)
            kbuf[hd] = f2bf(v);
          else
            vtbuf[((size_t)(b * NHEADS + hh) * 64 + dd) * NTOK + n] =
                f2bf(v + biasv[cc]);
        } else {
          Cout[(size_t)grow * CDIM + gcol] = v + bias0[gcol];
        }
      }
    }
  }
}

// ---------------- flash attention v4: split-KV x4, no VGPR cap ----------------
// 1176 blocks (one per bh x q-tile), 4 waves each own k-tiles kt = wv, wv+4, ...
// XCD-swizzled blockIdx (1176 = 8*147). LDS merge of (m,l,O) partials.
// NOTE: plain launch_bounds(256). (256,4) forced a 64-VGPR cap -> inner-loop
// scratch spills (VGPR_Count 84->64, dur 96->117us in R3). LDS (38.9KB) limits
// residency to 4 blocks/CU anyway; compiler lands <=128 VGPR -> 4 waves/SIMD.
__global__ __launch_bounds__(256) void attn_kernel(
    const unsigned short* __restrict__ qbuf,
    const unsigned short* __restrict__ kbuf,
    const unsigned short* __restrict__ vtbuf,
    const unsigned short* __restrict__ bias1T,
    const float* __restrict__ bias2,
    unsigned short* __restrict__ aout) {
  __shared__ float olds[4][64][36];
  __shared__ float mlds[4][64];
  __shared__ float llds[4][64];
  const int lane = threadIdx.x & 63;
  const int wv = threadIdx.x >> 6;
  const int wu = (blockIdx.x & 7) * 147 + (blockIdx.x >> 3);  // 0..1175
  const int bh = wu / 49;
  const int qt = wu - bh * 49;
  const int q0 = qt * 32;
  const int h = bh % NHEADS;
  const int b = bh / NHEADS;
  const int qlane = lane & 31;
  const int hi = lane >> 5;
  const int qn = q0 + qlane;
  const int qfr = qn / TPF;

  const unsigned short* qp = qbuf + (size_t)bh * NTOK * DHEAD;
  const unsigned short* kp = kbuf + (size_t)bh * NTOK * DHEAD;
  const unsigned short* vp = vtbuf + (size_t)bh * DHEAD * NTOK;
  const unsigned short* b1 = bias1T + (size_t)h * EXT1 * EXT1 + (q0 % AREA1) + qlane;
  const float* b2p = bias2 + h * 64 + qfr * 8;

  bf16x8 aq[4];
#pragma unroll
  for (int c = 0; c < 4; ++c)
    aq[c] = ld8(qp + (size_t)qn * DHEAD + c * 16 + hi * 8);

  f32x16 o0 = {}, o1 = {};
  float mrun = -1.0e30f, lrun = 0.f;

  bf16x8 kf[4];
#pragma unroll
  for (int c = 0; c < 4; ++c)
    kf[c] = ld8(kp + (size_t)(wv * 32 + qlane) * DHEAD + c * 16 + hi * 8);

  int base = wv * 32;  // kv0 % 197 for this wave's tile sequence
  for (int kt = wv; kt < NTOK / 32; kt += 4) {
    const int kv0 = kt * 32;
    f32x16 s = {};
#pragma unroll
    for (int c = 0; c < 4; ++c) s = mfma32(kf[c], aq[c], s);
    if (kt + 4 < NTOK / 32) {
#pragma unroll
      for (int c = 0; c < 4; ++c)
        kf[c] = ld8(kp + (size_t)(kv0 + 128 + qlane) * DHEAD + c * 16 + hi * 8);
    }
    bf16x8 vf0 = ld8(vp + (size_t)qlane * NTOK + kv0 + hi * 8);
    bf16x8 vf1 = ld8(vp + (size_t)qlane * NTOK + kv0 + 16 + hi * 8);
    bf16x8 vf2 = ld8(vp + (size_t)(32 + qlane) * NTOK + kv0 + hi * 8);
    bf16x8 vf3 = ld8(vp + (size_t)(32 + qlane) * NTOK + kv0 + 16 + hi * 8);

    const int kfl = kv0 / TPF;
    const int bnd = (kfl + 1) * TPF;
    const float b2lo = b2p[kfl];
    const float b2hi = b2p[kfl < 7 ? kfl + 1 : 7];
#pragma unroll
    for (int r = 0; r < 16; ++r) {
      const int kit = (r & 3) + 8 * (r >> 2) + 4 * hi;
      s[r] += bf2f(b1[(size_t)(base + kit) * EXT1]) +
              ((kv0 + kit) >= bnd ? b2hi : b2lo);
    }

    float tmax = s[0];
#pragma unroll
    for (int r = 1; r < 16; ++r) tmax = fmaxf(tmax, s[r]);
    tmax = fmaxf(tmax, __shfl_xor(tmax, 32));
    if (!__all(tmax - mrun <= 8.0f)) {  // T13 defer-max
      const float mnew = fmaxf(mrun, tmax);
      const float fac = __expf(mrun - mnew);
      lrun *= fac;
#pragma unroll
      for (int r = 0; r < 16; ++r) { o0[r] *= fac; o1[r] *= fac; }
      mrun = mnew;
    }
#pragma unroll
    for (int r = 0; r < 16; ++r) s[r] = __expf(s[r] - mrun);
    float ps = 0.f;
#pragma unroll
    for (int r = 0; r < 16; ++r) ps += s[r];
    ps += __shfl_xor(ps, 32);
    lrun += ps;

    unsigned int dw[8], e[8];
#pragma unroll
    for (int c = 0; c < 8; ++c) dw[c] = pack2(s[2 * c], s[2 * c + 1]);
#pragma unroll
    for (int c = 0; c < 8; ++c) e[c] = __shfl_xor(dw[c], 32);
    unsigned int f0[4], f1[4];
    f0[0] = hi ? e[2] : dw[0];  f0[1] = hi ? e[3] : dw[1];
    f0[2] = hi ? dw[2] : e[0];  f0[3] = hi ? dw[3] : e[1];
    f1[0] = hi ? e[6] : dw[4];  f1[1] = hi ? e[7] : dw[5];
    f1[2] = hi ? dw[6] : e[4];  f1[3] = hi ? dw[7] : e[5];
    const bf16x8 F0 = __builtin_bit_cast(bf16x8, *(ulonglong2*)f0);
    const bf16x8 F1 = __builtin_bit_cast(bf16x8, *(ulonglong2*)f1);

    o0 = mfma32(vf0, F0, o0);
    o0 = mfma32(vf1, F1, o0);
    o1 = mfma32(vf2, F0, o1);
    o1 = mfma32(vf3, F1, o1);

    base += 128;
    if (base >= AREA1) base -= AREA1;
  }

  // ---- merge partials across the 4 waves ----
  mlds[wv][lane] = mrun;
  llds[wv][lane] = lrun;
#pragma unroll
  for (int r = 0; r < 16; ++r) {
    olds[wv][lane][r] = o0[r];
    olds[wv][lane][16 + r] = o1[r];
  }
  __syncthreads();

  float msv[4];
#pragma unroll
  for (int s4 = 0; s4 < 4; ++s4) msv[s4] = mlds[s4][lane];
  float M = fmaxf(fmaxf(msv[0], msv[1]), fmaxf(msv[2], msv[3]));
  float wgt[4], L = 0.f;
#pragma unroll
  for (int s4 = 0; s4 < 4; ++s4) {
    wgt[s4] = __expf(msv[s4] - M);
    L += llds[s4][lane] * wgt[s4];
  }
  const float rinv = 1.0f / L;
  unsigned short* op = aout + (size_t)(b * NTOK + qn) * CDIM + h * 64;
#pragma unroll
  for (int gi = 0; gi < 2; ++gi) {
    const int g = wv * 2 + gi;
    float acc[4] = {0.f, 0.f, 0.f, 0.f};
#pragma unroll
    for (int s4 = 0; s4 < 4; ++s4) {
#pragma unroll
      for (int j = 0; j < 4; ++j)
        acc[j] += olds[s4][lane][4 * g + j] * wgt[s4];
    }
    const int dbase = (g < 4 ? 8 * g : 32 + 8 * (g - 4)) + 4 * hi;
    *(unsigned int*)(op + dbase) = pack2(acc[0] * rinv, acc[1] * rinv);
    *(unsigned int*)(op + dbase + 2) = pack2(acc[2] * rinv, acc[3] * rinv);
  }
}

extern "C" void kernel_launch(void* const* d_in, const int* in_sizes, int n_in,
                              void* d_out, int out_size, void* d_ws, size_t ws_size,
                              hipStream_t stream) {
  (void)in_sizes; (void)n_in; (void)out_size; (void)ws_size;
  const float* x        = (const float*)d_in[0];
  const float* qkv_w    = (const float*)d_in[1];
  const float* q_bias   = (const float*)d_in[2];
  const float* v_bias   = (const float*)d_in[3];
  const float* rp_table = (const float*)d_in[4];
  const float* rt_table = (const float*)d_in[5];
  const float* proj_w   = (const float*)d_in[6];
  const float* proj_b   = (const float*)d_in[7];
  const int* rp_index   = (const int*)d_in[8];
  const int* rt_index   = (const int*)d_in[9];

  char* ws = (char*)d_ws;
  unsigned short* xb     = (unsigned short*)(ws);
  unsigned short* qkvwb  = (unsigned short*)(ws + 4915200);
  unsigned short* projwb = (unsigned short*)(ws + 8454144);
  unsigned short* qbuf   = (unsigned short*)(ws + 9633792);
  unsigned short* kbuf   = (unsigned short*)(ws + 14450688);
  unsigned short* vtbuf  = (unsigned short*)(ws + 19267584);
  unsigned short* aout   = (unsigned short*)(ws + 24084480);
  unsigned short* bias1T = (unsigned short*)(ws + 28999680);
  float* bias2           = (float*)(ws + 30247424);

  conv_kernel<<<2048, 256, 0, stream>>>(x, qkv_w, proj_w, xb, qkvwb, projwb, aout);
  bias_kernel<<<(NHEADS * EXT1 * EXT1 + NHEADS * 64 + 255) / 256, 256, 0, stream>>>(
      rp_table, rt_table, rp_index, rt_index, bias1T, bias2);
  gemm_kernel<0><<<dim3(K3 / 128, MPAD / 128), 256, 0, stream>>>(
      xb, qkvwb, q_bias, v_bias, qbuf, kbuf, vtbuf, nullptr);
  attn_kernel<<<dim3(1176), 256, 0, stream>>>(
      qbuf, kbuf, vtbuf, bias1T, bias2, aout);
  gemm_kernel<1><<<dim3(CDIM / 128, MPAD / 128), 256, 0, stream>>>(
      aout, projwb, proj_b, nullptr, nullptr, nullptr, nullptr, (float*)d_out);
}

// Round 5
// 141.269 us; speedup vs baseline: 1.3704x; 1.1207x over previous
//
#include <hip/hip_runtime.h>
#include <hip/hip_bf16.h>

#define NHEADS 12
#define NFRAMES 8
#define NTOK 1568
#define CDIM 768
#define DHEAD 64
#define BATCH 2
#define MROWS (BATCH * NTOK) /* 3136 */
#define MPAD 3200
#define K3 (3 * CDIM)        /* 2304 */
#define AREA1 197
#define EXT1 228
#define TPF 196

typedef __bf16 bf16x8 __attribute__((ext_vector_type(8)));
typedef float f32x4 __attribute__((ext_vector_type(4)));
typedef float f32x16 __attribute__((ext_vector_type(16)));
typedef unsigned short u16x8 __attribute__((ext_vector_type(8)));

__device__ __forceinline__ unsigned short f2bf(float f) {
  return __builtin_bit_cast(unsigned short, (__bf16)f);
}
__device__ __forceinline__ float bf2f(unsigned short u) {
  unsigned int x = ((unsigned int)u) << 16;
  return __builtin_bit_cast(float, x);
}
__device__ __forceinline__ bf16x8 ld8(const unsigned short* p) {
  return __builtin_bit_cast(bf16x8, *(const u16x8*)p);
}
__device__ __forceinline__ f32x4 mfma16(bf16x8 a, bf16x8 b, f32x4 c) {
  return __builtin_amdgcn_mfma_f32_16x16x32_bf16(a, b, c, 0, 0, 0);
}
__device__ __forceinline__ f32x16 mfma32(bf16x8 a, bf16x8 b, f32x16 c) {
  return __builtin_amdgcn_mfma_f32_32x32x16_bf16(a, b, c, 0, 0, 0);
}
__device__ __forceinline__ unsigned int pack2(float lo, float hi) {
  return ((unsigned int)f2bf(hi) << 16) | (unsigned int)f2bf(lo);
}

// ---------------- conversion / packing ----------------
__global__ void conv_kernel(const float* __restrict__ x,
                            const float* __restrict__ qkv_w,
                            const float* __restrict__ proj_w,
                            unsigned short* __restrict__ xb,
                            unsigned short* __restrict__ qkvwb,
                            unsigned short* __restrict__ projwb,
                            unsigned short* __restrict__ aout) {
  const int XCH = MPAD * CDIM / 4;
  const int WCH = K3 * CDIM / 4;
  const int PCH = CDIM * CDIM / 4;
  const int ACH = (MPAD - MROWS) * CDIM / 4;
  const int total = XCH + WCH + PCH + ACH;
  for (int c = blockIdx.x * blockDim.x + threadIdx.x; c < total;
       c += gridDim.x * blockDim.x) {
    if (c < XCH) {
      int m = (c * 4) / CDIM;
      float4 v = make_float4(0.f, 0.f, 0.f, 0.f);
      if (m < MROWS) v = ((const float4*)x)[c];
      ushort4 o;
      o.x = f2bf(v.x); o.y = f2bf(v.y); o.z = f2bf(v.z); o.w = f2bf(v.w);
      ((ushort4*)xb)[c] = o;
    } else if (c < XCH + WCH) {
      int c2 = c - XCH;
      float4 v = ((const float4*)qkv_w)[c2];
      ushort4 o;
      o.x = f2bf(v.x); o.y = f2bf(v.y); o.z = f2bf(v.z); o.w = f2bf(v.w);
      ((ushort4*)qkvwb)[c2] = o;
    } else if (c < XCH + WCH + PCH) {
      int c2 = c - XCH - WCH;
      float4 v = ((const float4*)proj_w)[c2];
      ushort4 o;
      o.x = f2bf(v.x); o.y = f2bf(v.y); o.z = f2bf(v.z); o.w = f2bf(v.w);
      ((ushort4*)projwb)[c2] = o;
    } else {
      int c2 = c - XCH - WCH - PCH;
      ushort4 z; z.x = 0; z.y = 0; z.z = 0; z.w = 0;
      ((ushort4*)(aout + (size_t)MROWS * CDIM))[c2] = z;
    }
  }
}

// ---------------- bias table pre-gather ----------------
// bias1T[h][j=km_ext<228][i=qmod_ext<228] (bf16); bias2[h][qframe][kframe] (fp32).
__global__ void bias_kernel(const float* __restrict__ rpt,
                            const float* __restrict__ rtt,
                            const int* __restrict__ rpi,
                            const int* __restrict__ rti,
                            unsigned short* __restrict__ bias1T,
                            float* __restrict__ bias2) {
  int t = blockIdx.x * blockDim.x + threadIdx.x;
  const int n1 = NHEADS * EXT1 * EXT1;
  if (t < n1) {
    int h = t / (EXT1 * EXT1);
    int rem = t - h * (EXT1 * EXT1);
    int j = rem / EXT1;
    int i = rem - j * EXT1;
    int jm = (j >= AREA1) ? j - AREA1 : j;
    int im = (i >= AREA1) ? i - AREA1 : i;
    bias1T[t] = f2bf(rpt[rpi[im * AREA1 + jm] * NHEADS + h]);
  } else if (t < n1 + NHEADS * 64) {
    int t2 = t - n1;
    int h = t2 >> 6, ff = t2 & 63;
    bias2[t2] = rtt[rti[ff] * NHEADS + h];
  }
}

// ---------------- BM x BN MFMA GEMM (NT: both A,B row-major over K) ----------------
// Retiled R5: gemm0 128x64 -> 900 blocks (was 450 @1.76/CU), gemm1 64x64 -> 600
// blocks (was 150 @0.6/CU). Both were grid-starved; more blocks = latency hiding.
template <int MODE, int BM, int BN>
__global__ __launch_bounds__(256) void gemm_kernel(
    const unsigned short* __restrict__ A,
    const unsigned short* __restrict__ Bw,
    const float* __restrict__ bias0,   // q_bias (MODE0) / proj_b (MODE1)
    const float* __restrict__ biasv,   // v_bias (MODE0)
    unsigned short* __restrict__ qbuf,
    unsigned short* __restrict__ kbuf,
    unsigned short* __restrict__ vtbuf,
    float* __restrict__ Cout) {
  __shared__ unsigned short As[2][BM * 32];
  __shared__ unsigned short Bs[2][BN * 32];
  const int lane = threadIdx.x & 63;
  const int wv = threadIdx.x >> 6;
  const int tid = threadIdx.x;
  const int m0 = blockIdx.y * BM;
  const int n0 = blockIdx.x * BN;
  constexpr int WM = BM / 2, WN = BN / 2;

  auto stage = [&](int buf, int kt) {
    const int k0 = kt * 32;
#pragma unroll
    for (int ai = 0; ai < BM / 64; ++ai) {
      const int c = ai * 256 + tid;
      const int r = c >> 2, seg = c & 3;
      __builtin_amdgcn_global_load_lds(
          (const __attribute__((address_space(1))) void*)(A + (size_t)(m0 + r) * CDIM + k0 + seg * 8),
          (__attribute__((address_space(3))) void*)&As[buf][c * 8], 16, 0, 0);
    }
#pragma unroll
    for (int bi = 0; bi < BN / 64; ++bi) {
      const int c = bi * 256 + tid;
      const int r = c >> 2, seg = c & 3;
      __builtin_amdgcn_global_load_lds(
          (const __attribute__((address_space(1))) void*)(Bw + (size_t)(n0 + r) * CDIM + k0 + seg * 8),
          (__attribute__((address_space(3))) void*)&Bs[buf][c * 8], 16, 0, 0);
    }
  };

  f32x4 acc[WM / 16][WN / 16] = {};
  const int rbase = (wv >> 1) * WM;
  const int cbase = (wv & 1) * WN;

  stage(0, 0);
  __syncthreads();
  int cur = 0;
  for (int kt = 0; kt < CDIM / 32; ++kt) {
    if (kt + 1 < CDIM / 32) stage(cur ^ 1, kt + 1);
    bf16x8 af[WM / 16], bg[WN / 16];
#pragma unroll
    for (int i = 0; i < WM / 16; ++i)
      af[i] = ld8(&As[cur][(rbase + i * 16 + (lane & 15)) * 32 + (lane >> 4) * 8]);
#pragma unroll
    for (int j = 0; j < WN / 16; ++j)
      bg[j] = ld8(&Bs[cur][(cbase + j * 16 + (lane & 15)) * 32 + (lane >> 4) * 8]);
#pragma unroll
    for (int i = 0; i < WM / 16; ++i)
#pragma unroll
      for (int j = 0; j < WN / 16; ++j)
        acc[i][j] = mfma16(af[i], bg[j], acc[i][j]);
    __syncthreads();
    cur ^= 1;
  }

#pragma unroll
  for (int i = 0; i < WM / 16; ++i) {
#pragma unroll
    for (int j = 0; j < WN / 16; ++j) {
#pragma unroll
      for (int r = 0; r < 4; ++r) {
        int grow = m0 + rbase + i * 16 + (lane >> 4) * 4 + r;
        int gcol = n0 + cbase + j * 16 + (lane & 15);
        if (grow >= MROWS) continue;
        float v = acc[i][j][r];
        if (MODE == 0) {
          int which = gcol / CDIM;
          int cc = gcol - which * CDIM;
          int hh = cc >> 6, dd = cc & 63;
          int b = grow / NTOK, n = grow - b * NTOK;
          size_t hd = ((size_t)(b * NHEADS + hh) * NTOK + n) * 64 + dd;
          if (which == 0)
            qbuf[hd] = f2bf((v + bias0[cc]) * 0.125f);
          else if (which == 1)
            kbuf[hd] = f2bf(v);
          else
            vtbuf[((size_t)(b * NHEADS + hh) * 64 + dd) * NTOK + n] =
                f2bf(v + biasv[cc]);
        } else {
          Cout[(size_t)grow * CDIM + gcol] = v + bias0[gcol];
        }
      }
    }
  }
}

// ---------------- flash attention v5: split-KV x4, slim LDS two-phase merge --------
// 1176 blocks (one per bh x q-tile), 4 waves each own k-tiles kt = wv, wv+4, ...
// XCD-swizzled blockIdx (1176 = 8*147).
// R5: LDS 38.9KB -> 21.5KB (two-phase fp32 merge, stride-19 rows) -- R4 showed
// occupancy 16% vs static 50%, pointing at LDS-limited block residency.
// T5 setprio around MFMA clusters (attn regime: m191 +4-7%).
__global__ __launch_bounds__(256) void attn_kernel(
    const unsigned short* __restrict__ qbuf,
    const unsigned short* __restrict__ kbuf,
    const unsigned short* __restrict__ vtbuf,
    const unsigned short* __restrict__ bias1T,
    const float* __restrict__ bias2,
    unsigned short* __restrict__ aout) {
  __shared__ float olds[4][64][19];  // 19.5KB; rows: 16 O + m + l + pad (odd stride)
  const int lane = threadIdx.x & 63;
  const int wv = threadIdx.x >> 6;
  const int wu = (blockIdx.x & 7) * 147 + (blockIdx.x >> 3);  // 0..1175
  const int bh = wu / 49;
  const int qt = wu - bh * 49;
  const int q0 = qt * 32;
  const int h = bh % NHEADS;
  const int b = bh / NHEADS;
  const int qlane = lane & 31;
  const int hi = lane >> 5;
  const int qn = q0 + qlane;
  const int qfr = qn / TPF;

  const unsigned short* qp = qbuf + (size_t)bh * NTOK * DHEAD;
  const unsigned short* kp = kbuf + (size_t)bh * NTOK * DHEAD;
  const unsigned short* vp = vtbuf + (size_t)bh * DHEAD * NTOK;
  const unsigned short* b1 = bias1T + (size_t)h * EXT1 * EXT1 + (q0 % AREA1) + qlane;
  const float* b2p = bias2 + h * 64 + qfr * 8;

  bf16x8 aq[4];
#pragma unroll
  for (int c = 0; c < 4; ++c)
    aq[c] = ld8(qp + (size_t)qn * DHEAD + c * 16 + hi * 8);

  f32x16 o0 = {}, o1 = {};
  float mrun = -1.0e30f, lrun = 0.f;

  bf16x8 kf[4];
#pragma unroll
  for (int c = 0; c < 4; ++c)
    kf[c] = ld8(kp + (size_t)(wv * 32 + qlane) * DHEAD + c * 16 + hi * 8);

  int base = wv * 32;  // kv0 % 197 for this wave's tile sequence
  for (int kt = wv; kt < NTOK / 32; kt += 4) {
    const int kv0 = kt * 32;
    f32x16 s = {};
    __builtin_amdgcn_s_setprio(1);
#pragma unroll
    for (int c = 0; c < 4; ++c) s = mfma32(kf[c], aq[c], s);
    __builtin_amdgcn_s_setprio(0);
    if (kt + 4 < NTOK / 32) {
#pragma unroll
      for (int c = 0; c < 4; ++c)
        kf[c] = ld8(kp + (size_t)(kv0 + 128 + qlane) * DHEAD + c * 16 + hi * 8);
    }
    bf16x8 vf0 = ld8(vp + (size_t)qlane * NTOK + kv0 + hi * 8);
    bf16x8 vf1 = ld8(vp + (size_t)qlane * NTOK + kv0 + 16 + hi * 8);
    bf16x8 vf2 = ld8(vp + (size_t)(32 + qlane) * NTOK + kv0 + hi * 8);
    bf16x8 vf3 = ld8(vp + (size_t)(32 + qlane) * NTOK + kv0 + 16 + hi * 8);

    const int kfl = kv0 / TPF;
    const int bnd = (kfl + 1) * TPF;
    const float b2lo = b2p[kfl];
    const float b2hi = b2p[kfl < 7 ? kfl + 1 : 7];
#pragma unroll
    for (int r = 0; r < 16; ++r) {
      const int kit = (r & 3) + 8 * (r >> 2) + 4 * hi;
      s[r] += bf2f(b1[(size_t)(base + kit) * EXT1]) +
              ((kv0 + kit) >= bnd ? b2hi : b2lo);
    }

    float tmax = s[0];
#pragma unroll
    for (int r = 1; r < 16; ++r) tmax = fmaxf(tmax, s[r]);
    tmax = fmaxf(tmax, __shfl_xor(tmax, 32));
    if (!__all(tmax - mrun <= 8.0f)) {  // T13 defer-max
      const float mnew = fmaxf(mrun, tmax);
      const float fac = __expf(mrun - mnew);
      lrun *= fac;
#pragma unroll
      for (int r = 0; r < 16; ++r) { o0[r] *= fac; o1[r] *= fac; }
      mrun = mnew;
    }
#pragma unroll
    for (int r = 0; r < 16; ++r) s[r] = __expf(s[r] - mrun);
    float ps = 0.f;
#pragma unroll
    for (int r = 0; r < 16; ++r) ps += s[r];
    ps += __shfl_xor(ps, 32);
    lrun += ps;

    unsigned int dw[8], e[8];
#pragma unroll
    for (int c = 0; c < 8; ++c) dw[c] = pack2(s[2 * c], s[2 * c + 1]);
#pragma unroll
    for (int c = 0; c < 8; ++c) e[c] = __shfl_xor(dw[c], 32);
    unsigned int f0[4], f1[4];
    f0[0] = hi ? e[2] : dw[0];  f0[1] = hi ? e[3] : dw[1];
    f0[2] = hi ? dw[2] : e[0];  f0[3] = hi ? dw[3] : e[1];
    f1[0] = hi ? e[6] : dw[4];  f1[1] = hi ? e[7] : dw[5];
    f1[2] = hi ? dw[6] : e[4];  f1[3] = hi ? dw[7] : e[5];
    const bf16x8 F0 = __builtin_bit_cast(bf16x8, *(ulonglong2*)f0);
    const bf16x8 F1 = __builtin_bit_cast(bf16x8, *(ulonglong2*)f1);

    __builtin_amdgcn_s_setprio(1);
    o0 = mfma32(vf0, F0, o0);
    o0 = mfma32(vf1, F1, o0);
    o1 = mfma32(vf2, F0, o1);
    o1 = mfma32(vf3, F1, o1);
    __builtin_amdgcn_s_setprio(0);

    base += 128;
    if (base >= AREA1) base -= AREA1;
  }

  // ---- two-phase merge: phase A = o0 (+m,l), phase B = o1 (reuses buffer) ----
  float* row = &olds[wv][lane][0];
#pragma unroll
  for (int r = 0; r < 16; ++r) row[r] = o0[r];
  row[16] = mrun;
  row[17] = lrun;
  __syncthreads();

  float wgt[4], L = 0.f, M = -1.0e30f;
#pragma unroll
  for (int s4 = 0; s4 < 4; ++s4) M = fmaxf(M, olds[s4][lane][16]);
#pragma unroll
  for (int s4 = 0; s4 < 4; ++s4) {
    wgt[s4] = __expf(olds[s4][lane][16] - M);
    L += olds[s4][lane][17] * wgt[s4];
  }
  const float rinv = 1.0f / L;
  unsigned short* op = aout + (size_t)(b * NTOK + qn) * CDIM + h * 64;
  const int dbase = 8 * wv + 4 * hi;  // reg-group wv of o0/o1 -> d = 8*wv+4*hi+j
  {
    float acc[4] = {0.f, 0.f, 0.f, 0.f};
#pragma unroll
    for (int s4 = 0; s4 < 4; ++s4)
#pragma unroll
      for (int j = 0; j < 4; ++j)
        acc[j] += olds[s4][lane][4 * wv + j] * wgt[s4];
    *(unsigned int*)(op + dbase) = pack2(acc[0] * rinv, acc[1] * rinv);
    *(unsigned int*)(op + dbase + 2) = pack2(acc[2] * rinv, acc[3] * rinv);
  }
  __syncthreads();
#pragma unroll
  for (int r = 0; r < 16; ++r) row[r] = o1[r];
  __syncthreads();
  {
    float acc[4] = {0.f, 0.f, 0.f, 0.f};
#pragma unroll
    for (int s4 = 0; s4 < 4; ++s4)
#pragma unroll
      for (int j = 0; j < 4; ++j)
        acc[j] += olds[s4][lane][4 * wv + j] * wgt[s4];
    *(unsigned int*)(op + 32 + dbase) = pack2(acc[0] * rinv, acc[1] * rinv);
    *(unsigned int*)(op + 32 + dbase + 2) = pack2(acc[2] * rinv, acc[3] * rinv);
  }
}

extern "C" void kernel_launch(void* const* d_in, const int* in_sizes, int n_in,
                              void* d_out, int out_size, void* d_ws, size_t ws_size,
                              hipStream_t stream) {
  (void)in_sizes; (void)n_in; (void)out_size; (void)ws_size;
  const float* x        = (const float*)d_in[0];
  const float* qkv_w    = (const float*)d_in[1];
  const float* q_bias   = (const float*)d_in[2];
  const float* v_bias   = (const float*)d_in[3];
  const float* rp_table = (const float*)d_in[4];
  const float* rt_table = (const float*)d_in[5];
  const float* proj_w   = (const float*)d_in[6];
  const float* proj_b   = (const float*)d_in[7];
  const int* rp_index   = (const int*)d_in[8];
  const int* rt_index   = (const int*)d_in[9];

  char* ws = (char*)d_ws;
  unsigned short* xb     = (unsigned short*)(ws);
  unsigned short* qkvwb  = (unsigned short*)(ws + 4915200);
  unsigned short* projwb = (unsigned short*)(ws + 8454144);
  unsigned short* qbuf   = (unsigned short*)(ws + 9633792);
  unsigned short* kbuf   = (unsigned short*)(ws + 14450688);
  unsigned short* vtbuf  = (unsigned short*)(ws + 19267584);
  unsigned short* aout   = (unsigned short*)(ws + 24084480);
  unsigned short* bias1T = (unsigned short*)(ws + 28999680);
  float* bias2           = (float*)(ws + 30247424);

  conv_kernel<<<2048, 256, 0, stream>>>(x, qkv_w, proj_w, xb, qkvwb, projwb, aout);
  bias_kernel<<<(NHEADS * EXT1 * EXT1 + NHEADS * 64 + 255) / 256, 256, 0, stream>>>(
      rp_table, rt_table, rp_index, rt_index, bias1T, bias2);
  gemm_kernel<0, 128, 64><<<dim3(K3 / 64, MPAD / 128), 256, 0, stream>>>(
      xb, qkvwb, q_bias, v_bias, qbuf, kbuf, vtbuf, nullptr);
  attn_kernel<<<dim3(1176), 256, 0, stream>>>(
      qbuf, kbuf, vtbuf, bias1T, bias2, aout);
  gemm_kernel<1, 64, 64><<<dim3(CDIM / 64, MPAD / 64), 256, 0, stream>>>(
      aout, projwb, proj_b, nullptr, nullptr, nullptr, nullptr, (float*)d_out);
}

// Round 6
// 130.128 us; speedup vs baseline: 1.4877x; 1.0856x over previous
//
#include <hip/hip_runtime.h>
#include <hip/hip_bf16.h>

#define NHEADS 12
#define NFRAMES 8
#define NTOK 1568
#define CDIM 768
#define DHEAD 64
#define BATCH 2
#define MROWS (BATCH * NTOK) /* 3136 */
#define MPAD 3200
#define K3 (3 * CDIM)        /* 2304 */
#define AREA1 197
#define EXT1 228
#define TPF 196
#define LOG2E 1.4426950408889634f

typedef __bf16 bf16x8 __attribute__((ext_vector_type(8)));
typedef float f32x4 __attribute__((ext_vector_type(4)));
typedef float f32x16 __attribute__((ext_vector_type(16)));
typedef unsigned short u16x8 __attribute__((ext_vector_type(8)));

#if __has_builtin(__builtin_amdgcn_exp2f)
#define EXP2(x) __builtin_amdgcn_exp2f(x)
#else
#define EXP2(x) exp2f(x)
#endif

__device__ __forceinline__ unsigned short f2bf(float f) {
  return __builtin_bit_cast(unsigned short, (__bf16)f);
}
__device__ __forceinline__ float bf2f(unsigned short u) {
  unsigned int x = ((unsigned int)u) << 16;
  return __builtin_bit_cast(float, x);
}
__device__ __forceinline__ bf16x8 ld8(const unsigned short* p) {
  return __builtin_bit_cast(bf16x8, *(const u16x8*)p);
}
__device__ __forceinline__ f32x4 mfma16(bf16x8 a, bf16x8 b, f32x4 c) {
  return __builtin_amdgcn_mfma_f32_16x16x32_bf16(a, b, c, 0, 0, 0);
}
__device__ __forceinline__ f32x16 mfma32(bf16x8 a, bf16x8 b, f32x16 c) {
  return __builtin_amdgcn_mfma_f32_32x32x16_bf16(a, b, c, 0, 0, 0);
}
__device__ __forceinline__ unsigned int pack2(float lo, float hi) {
  return ((unsigned int)f2bf(hi) << 16) | (unsigned int)f2bf(lo);
}

// ---------------- conversion / packing ----------------
__global__ void conv_kernel(const float* __restrict__ x,
                            const float* __restrict__ qkv_w,
                            const float* __restrict__ proj_w,
                            unsigned short* __restrict__ xb,
                            unsigned short* __restrict__ qkvwb,
                            unsigned short* __restrict__ projwb,
                            unsigned short* __restrict__ aout) {
  const int XCH = MPAD * CDIM / 4;
  const int WCH = K3 * CDIM / 4;
  const int PCH = CDIM * CDIM / 4;
  const int ACH = (MPAD - MROWS) * CDIM / 4;
  const int total = XCH + WCH + PCH + ACH;
  for (int c = blockIdx.x * blockDim.x + threadIdx.x; c < total;
       c += gridDim.x * blockDim.x) {
    if (c < XCH) {
      int m = (c * 4) / CDIM;
      float4 v = make_float4(0.f, 0.f, 0.f, 0.f);
      if (m < MROWS) v = ((const float4*)x)[c];
      ushort4 o;
      o.x = f2bf(v.x); o.y = f2bf(v.y); o.z = f2bf(v.z); o.w = f2bf(v.w);
      ((ushort4*)xb)[c] = o;
    } else if (c < XCH + WCH) {
      int c2 = c - XCH;
      float4 v = ((const float4*)qkv_w)[c2];
      ushort4 o;
      o.x = f2bf(v.x); o.y = f2bf(v.y); o.z = f2bf(v.z); o.w = f2bf(v.w);
      ((ushort4*)qkvwb)[c2] = o;
    } else if (c < XCH + WCH + PCH) {
      int c2 = c - XCH - WCH;
      float4 v = ((const float4*)proj_w)[c2];
      ushort4 o;
      o.x = f2bf(v.x); o.y = f2bf(v.y); o.z = f2bf(v.z); o.w = f2bf(v.w);
      ((ushort4*)projwb)[c2] = o;
    } else {
      int c2 = c - XCH - WCH - PCH;
      ushort4 z; z.x = 0; z.y = 0; z.z = 0; z.w = 0;
      ((ushort4*)(aout + (size_t)MROWS * CDIM))[c2] = z;
    }
  }
}

// ---------------- bias table pre-gather ----------------
// bias1Q[h][i=qmod<197][j=km_ext<228] (bf16, pre-scaled by log2e): per-lane row
// layout -> 16 imm-offset loads per attn tile.  bias2[h][qframe][kframe] (f32, xlog2e).
__global__ void bias_kernel(const float* __restrict__ rpt,
                            const float* __restrict__ rtt,
                            const int* __restrict__ rpi,
                            const int* __restrict__ rti,
                            unsigned short* __restrict__ bias1Q,
                            float* __restrict__ bias2) {
  int t = blockIdx.x * blockDim.x + threadIdx.x;
  const int n1 = NHEADS * AREA1 * EXT1;
  if (t < n1) {
    int h = t / (AREA1 * EXT1);
    int rem = t - h * (AREA1 * EXT1);
    int i = rem / EXT1;                 // qmod
    int j = rem - i * EXT1;             // km extended
    int jm = (j >= AREA1) ? j - AREA1 : j;
    bias1Q[t] = f2bf(rpt[rpi[i * AREA1 + jm] * NHEADS + h] * LOG2E);
  } else if (t < n1 + NHEADS * 64) {
    int t2 = t - n1;
    int h = t2 >> 6, ff = t2 & 63;
    bias2[t2] = rtt[rti[ff] * NHEADS + h] * LOG2E;
  }
}

// ---------------- BM x BN MFMA GEMM (NT: both A,B row-major over K) ----------------
template <int MODE, int BM, int BN>
__global__ __launch_bounds__(256) void gemm_kernel(
    const unsigned short* __restrict__ A,
    const unsigned short* __restrict__ Bw,
    const float* __restrict__ bias0,   // q_bias (MODE0) / proj_b (MODE1)
    const float* __restrict__ biasv,   // v_bias (MODE0)
    unsigned short* __restrict__ qbuf,
    unsigned short* __restrict__ kbuf,
    unsigned short* __restrict__ vtbuf,
    float* __restrict__ Cout) {
  __shared__ unsigned short As[2][BM * 32];
  __shared__ unsigned short Bs[2][BN * 32];
  const int lane = threadIdx.x & 63;
  const int wv = threadIdx.x >> 6;
  const int tid = threadIdx.x;
  const int m0 = blockIdx.y * BM;
  const int n0 = blockIdx.x * BN;
  constexpr int WM = BM / 2, WN = BN / 2;

  auto stage = [&](int buf, int kt) {
    const int k0 = kt * 32;
#pragma unroll
    for (int ai = 0; ai < BM / 64; ++ai) {
      const int c = ai * 256 + tid;
      const int r = c >> 2, seg = c & 3;
      __builtin_amdgcn_global_load_lds(
          (const __attribute__((address_space(1))) void*)(A + (size_t)(m0 + r) * CDIM + k0 + seg * 8),
          (__attribute__((address_space(3))) void*)&As[buf][c * 8], 16, 0, 0);
    }
#pragma unroll
    for (int bi = 0; bi < BN / 64; ++bi) {
      const int c = bi * 256 + tid;
      const int r = c >> 2, seg = c & 3;
      __builtin_amdgcn_global_load_lds(
          (const __attribute__((address_space(1))) void*)(Bw + (size_t)(n0 + r) * CDIM + k0 + seg * 8),
          (__attribute__((address_space(3))) void*)&Bs[buf][c * 8], 16, 0, 0);
    }
  };

  f32x4 acc[WM / 16][WN / 16] = {};
  const int rbase = (wv >> 1) * WM;
  const int cbase = (wv & 1) * WN;

  stage(0, 0);
  __syncthreads();
  int cur = 0;
  for (int kt = 0; kt < CDIM / 32; ++kt) {
    if (kt + 1 < CDIM / 32) stage(cur ^ 1, kt + 1);
    bf16x8 af[WM / 16], bg[WN / 16];
#pragma unroll
    for (int i = 0; i < WM / 16; ++i)
      af[i] = ld8(&As[cur][(rbase + i * 16 + (lane & 15)) * 32 + (lane >> 4) * 8]);
#pragma unroll
    for (int j = 0; j < WN / 16; ++j)
      bg[j] = ld8(&Bs[cur][(cbase + j * 16 + (lane & 15)) * 32 + (lane >> 4) * 8]);
#pragma unroll
    for (int i = 0; i < WM / 16; ++i)
#pragma unroll
      for (int j = 0; j < WN / 16; ++j)
        acc[i][j] = mfma16(af[i], bg[j], acc[i][j]);
    __syncthreads();
    cur ^= 1;
  }

#pragma unroll
  for (int i = 0; i < WM / 16; ++i) {
#pragma unroll
    for (int j = 0; j < WN / 16; ++j) {
#pragma unroll
      for (int r = 0; r < 4; ++r) {
        int grow = m0 + rbase + i * 16 + (lane >> 4) * 4 + r;
        int gcol = n0 + cbase + j * 16 + (lane & 15);
        if (grow >= MROWS) continue;
        float v = acc[i][j][r];
        if (MODE == 0) {
          int which = gcol / CDIM;
          int cc = gcol - which * CDIM;
          int hh = cc >> 6, dd = cc & 63;
          int b = grow / NTOK, n = grow - b * NTOK;
          size_t hd = ((size_t)(b * NHEADS + hh) * NTOK + n) * 64 + dd;
          if (which == 0)
            qbuf[hd] = f2bf((v + bias0[cc]) * (0.125f * LOG2E));  // exp2-domain fold
          else if (which == 1)
            kbuf[hd] = f2bf(v);
          else
            vtbuf[((size_t)(b * NHEADS + hh) * 64 + dd) * NTOK + n] =
                f2bf(v + biasv[cc]);
        } else {
          Cout[(size_t)grow * CDIM + gcol] = v + bias0[gcol];
        }
      }
    }
  }
}

// ---------------- flash attention v6: bias-in-C-init, exp2 domain ----------------
// 1176 blocks (one per bh x q-tile), 4 waves each own k-tiles kt = wv, wv+4, ...
// XCD-swizzled blockIdx (1176 = 8*147). Two-phase LDS merge.
// R6: bias1 loaded per-lane-row at imm offsets, software-pipelined, fused into
// the QK MFMA accumulator init; bias2 folded into the exp2 subtrahend on
// non-frame-crossing tiles (wave-uniform branch); exp -> exp2 (tables & Q
// pre-scaled by log2e).  Targets the ~300 VALU/tile R5 profile (VALUBusy 43%).
__global__ __launch_bounds__(256) void attn_kernel(
    const unsigned short* __restrict__ qbuf,
    const unsigned short* __restrict__ kbuf,
    const unsigned short* __restrict__ vtbuf,
    const unsigned short* __restrict__ bias1Q,
    const float* __restrict__ bias2,
    unsigned short* __restrict__ aout) {
  __shared__ float olds[4][64][19];
  const int lane = threadIdx.x & 63;
  const int wv = threadIdx.x >> 6;
  const int wu = (blockIdx.x & 7) * 147 + (blockIdx.x >> 3);  // 0..1175
  const int bh = wu / 49;
  const int qt = wu - bh * 49;
  const int q0 = qt * 32;
  const int h = bh % NHEADS;
  const int b = bh / NHEADS;
  const int qlane = lane & 31;
  const int hi = lane >> 5;
  const int hi4 = hi * 4;
  const int qn = q0 + qlane;
  const int qfr = qn / TPF;
  const int qmod = qn % AREA1;

  const unsigned short* qp = qbuf + (size_t)bh * NTOK * DHEAD;
  const unsigned short* kp = kbuf + (size_t)bh * NTOK * DHEAD;
  const unsigned short* vp = vtbuf + (size_t)bh * DHEAD * NTOK;
  const unsigned short* bq = bias1Q + ((size_t)h * AREA1 + qmod) * EXT1 + hi4;
  const float* b2q = bias2 + h * 64 + qfr * 8;

  bf16x8 aq[4];
#pragma unroll
  for (int c = 0; c < 4; ++c)
    aq[c] = ld8(qp + (size_t)qn * DHEAD + c * 16 + hi * 8);

  f32x16 o0 = {}, o1 = {};
  float mrun = -1.0e30f, lrun = 0.f;

  bf16x8 kf[4];
#pragma unroll
  for (int c = 0; c < 4; ++c)
    kf[c] = ld8(kp + (size_t)(wv * 32 + qlane) * DHEAD + c * 16 + hi * 8);

  // pipelined bias state for the current tile
  unsigned short ub[16];
  float b2lo, b2hi;
  int base = wv * 32;  // kv0 % 197
  int kfl = (wv * 32) / TPF;
  {
    const unsigned short* bp = bq + base;
#pragma unroll
    for (int r = 0; r < 16; ++r) ub[r] = bp[(r & 3) + 8 * (r >> 2)];
    b2lo = b2q[kfl];
    b2hi = b2q[kfl < 7 ? kfl + 1 : 7];
  }

  for (int kt = wv; kt < NTOK / 32; kt += 4) {
    const int kv0 = kt * 32;
    // C-init = bias1 (log2e domain); QK^T accumulates on top
    f32x16 s;
#pragma unroll
    for (int r = 0; r < 16; ++r) s[r] = bf2f(ub[r]);
    __builtin_amdgcn_s_setprio(1);
#pragma unroll
    for (int c = 0; c < 4; ++c) s = mfma32(kf[c], aq[c], s);
    __builtin_amdgcn_s_setprio(0);

    // prefetch next tile's K, bias1 row chunk, b2 scalars
    int basen = base + 128; if (basen >= AREA1) basen -= AREA1;
    int kfln = kfl;
    float nb2lo = 0.f, nb2hi = 0.f;
    if (kt + 4 < NTOK / 32) {
#pragma unroll
      for (int c = 0; c < 4; ++c)
        kf[c] = ld8(kp + (size_t)(kv0 + 128 + qlane) * DHEAD + c * 16 + hi * 8);
      const unsigned short* bp = bq + basen;
#pragma unroll
      for (int r = 0; r < 16; ++r) ub[r] = bp[(r & 3) + 8 * (r >> 2)];
      kfln = (kv0 + 128) / TPF;
      nb2lo = b2q[kfln];
      nb2hi = b2q[kfln < 7 ? kfln + 1 : 7];
    }
    bf16x8 vf0 = ld8(vp + (size_t)qlane * NTOK + kv0 + hi * 8);
    bf16x8 vf1 = ld8(vp + (size_t)qlane * NTOK + kv0 + 16 + hi * 8);
    bf16x8 vf2 = ld8(vp + (size_t)(32 + qlane) * NTOK + kv0 + hi * 8);
    bf16x8 vf3 = ld8(vp + (size_t)(32 + qlane) * NTOK + kv0 + 16 + hi * 8);

    // bias2: uniform per tile unless the tile crosses a frame boundary
    const int ccr = (kfl + 1) * TPF - kv0;  // in (0, 196]
    if (ccr < 32) {
      const float dlt = b2hi - b2lo;
#pragma unroll
      for (int r = 0; r < 16; ++r)
        s[r] += ((r & 3) + 8 * (r >> 2) + hi4 >= ccr) ? dlt : 0.f;
    }

    // tree max over 16 regs + cross-half
    float m0a = fmaxf(s[0], s[1]),  m1a = fmaxf(s[2], s[3]);
    float m2a = fmaxf(s[4], s[5]),  m3a = fmaxf(s[6], s[7]);
    float m4a = fmaxf(s[8], s[9]),  m5a = fmaxf(s[10], s[11]);
    float m6a = fmaxf(s[12], s[13]), m7a = fmaxf(s[14], s[15]);
    float tmax = fmaxf(fmaxf(fmaxf(m0a, m1a), fmaxf(m2a, m3a)),
                       fmaxf(fmaxf(m4a, m5a), fmaxf(m6a, m7a)));
    tmax = fmaxf(tmax, __shfl_xor(tmax, 32));
    const float tb = tmax + b2lo;
    if (!__all(tb - mrun <= 11.5f)) {  // T13 defer-max (log2 domain)
      const float mnew = fmaxf(mrun, tb);
      const float fac = EXP2(mrun - mnew);
      lrun *= fac;
#pragma unroll
      for (int r = 0; r < 16; ++r) { o0[r] *= fac; o1[r] *= fac; }
      mrun = mnew;
    }
    const float mm = mrun - b2lo;  // fold uniform bias2 into subtrahend
#pragma unroll
    for (int r = 0; r < 16; ++r) s[r] = EXP2(s[r] - mm);
    float s0a = s[0] + s[1] + s[2] + s[3];
    float s1a = s[4] + s[5] + s[6] + s[7];
    float s2a = s[8] + s[9] + s[10] + s[11];
    float s3a = s[12] + s[13] + s[14] + s[15];
    float ps = (s0a + s1a) + (s2a + s3a);
    ps += __shfl_xor(ps, 32);
    lrun += ps;

    unsigned int dw[8], e[8];
#pragma unroll
    for (int c = 0; c < 8; ++c) dw[c] = pack2(s[2 * c], s[2 * c + 1]);
#pragma unroll
    for (int c = 0; c < 8; ++c) e[c] = __shfl_xor(dw[c], 32);
    unsigned int f0[4], f1[4];
    f0[0] = hi ? e[2] : dw[0];  f0[1] = hi ? e[3] : dw[1];
    f0[2] = hi ? dw[2] : e[0];  f0[3] = hi ? dw[3] : e[1];
    f1[0] = hi ? e[6] : dw[4];  f1[1] = hi ? e[7] : dw[5];
    f1[2] = hi ? dw[6] : e[4];  f1[3] = hi ? dw[7] : e[5];
    const bf16x8 F0 = __builtin_bit_cast(bf16x8, *(ulonglong2*)f0);
    const bf16x8 F1 = __builtin_bit_cast(bf16x8, *(ulonglong2*)f1);

    __builtin_amdgcn_s_setprio(1);
    o0 = mfma32(vf0, F0, o0);
    o0 = mfma32(vf1, F1, o0);
    o1 = mfma32(vf2, F0, o1);
    o1 = mfma32(vf3, F1, o1);
    __builtin_amdgcn_s_setprio(0);

    base = basen;
    kfl = kfln;
    b2lo = nb2lo;
    b2hi = nb2hi;
  }

  // ---- two-phase merge: phase A = o0 (+m,l), phase B = o1 (reuses buffer) ----
  float* row = &olds[wv][lane][0];
#pragma unroll
  for (int r = 0; r < 16; ++r) row[r] = o0[r];
  row[16] = mrun;
  row[17] = lrun;
  __syncthreads();

  float wgt[4], L = 0.f, M = -1.0e30f;
#pragma unroll
  for (int s4 = 0; s4 < 4; ++s4) M = fmaxf(M, olds[s4][lane][16]);
#pragma unroll
  for (int s4 = 0; s4 < 4; ++s4) {
    wgt[s4] = EXP2(olds[s4][lane][16] - M);
    L += olds[s4][lane][17] * wgt[s4];
  }
  const float rinv = 1.0f / L;
  unsigned short* op = aout + (size_t)(b * NTOK + qn) * CDIM + h * 64;
  const int dbase = 8 * wv + 4 * hi;
  {
    float acc[4] = {0.f, 0.f, 0.f, 0.f};
#pragma unroll
    for (int s4 = 0; s4 < 4; ++s4)
#pragma unroll
      for (int j = 0; j < 4; ++j)
        acc[j] += olds[s4][lane][4 * wv + j] * wgt[s4];
    *(unsigned int*)(op + dbase) = pack2(acc[0] * rinv, acc[1] * rinv);
    *(unsigned int*)(op + dbase + 2) = pack2(acc[2] * rinv, acc[3] * rinv);
  }
  __syncthreads();
#pragma unroll
  for (int r = 0; r < 16; ++r) row[r] = o1[r];
  __syncthreads();
  {
    float acc[4] = {0.f, 0.f, 0.f, 0.f};
#pragma unroll
    for (int s4 = 0; s4 < 4; ++s4)
#pragma unroll
      for (int j = 0; j < 4; ++j)
        acc[j] += olds[s4][lane][4 * wv + j] * wgt[s4];
    *(unsigned int*)(op + 32 + dbase) = pack2(acc[0] * rinv, acc[1] * rinv);
    *(unsigned int*)(op + 32 + dbase + 2) = pack2(acc[2] * rinv, acc[3] * rinv);
  }
}

extern "C" void kernel_launch(void* const* d_in, const int* in_sizes, int n_in,
                              void* d_out, int out_size, void* d_ws, size_t ws_size,
                              hipStream_t stream) {
  (void)in_sizes; (void)n_in; (void)out_size; (void)ws_size;
  const float* x        = (const float*)d_in[0];
  const float* qkv_w    = (const float*)d_in[1];
  const float* q_bias   = (const float*)d_in[2];
  const float* v_bias   = (const float*)d_in[3];
  const float* rp_table = (const float*)d_in[4];
  const float* rt_table = (const float*)d_in[5];
  const float* proj_w   = (const float*)d_in[6];
  const float* proj_b   = (const float*)d_in[7];
  const int* rp_index   = (const int*)d_in[8];
  const int* rt_index   = (const int*)d_in[9];

  char* ws = (char*)d_ws;
  unsigned short* xb     = (unsigned short*)(ws);
  unsigned short* qkvwb  = (unsigned short*)(ws + 4915200);
  unsigned short* projwb = (unsigned short*)(ws + 8454144);
  unsigned short* qbuf   = (unsigned short*)(ws + 9633792);
  unsigned short* kbuf   = (unsigned short*)(ws + 14450688);
  unsigned short* vtbuf  = (unsigned short*)(ws + 19267584);
  unsigned short* aout   = (unsigned short*)(ws + 24084480);
  unsigned short* bias1Q = (unsigned short*)(ws + 28999680);  // 12*197*228*2 = 1,078,224 B
  float* bias2           = (float*)(ws + 30247424);

  conv_kernel<<<2048, 256, 0, stream>>>(x, qkv_w, proj_w, xb, qkvwb, projwb, aout);
  bias_kernel<<<(NHEADS * AREA1 * EXT1 + NHEADS * 64 + 255) / 256, 256, 0, stream>>>(
      rp_table, rt_table, rp_index, rt_index, bias1Q, bias2);
  gemm_kernel<0, 128, 64><<<dim3(K3 / 64, MPAD / 128), 256, 0, stream>>>(
      xb, qkvwb, q_bias, v_bias, qbuf, kbuf, vtbuf, nullptr);
  attn_kernel<<<dim3(1176), 256, 0, stream>>>(
      qbuf, kbuf, vtbuf, bias1Q, bias2, aout);
  gemm_kernel<1, 64, 64><<<dim3(CDIM / 64, MPAD / 64), 256, 0, stream>>>(
      aout, projwb, proj_b, nullptr, nullptr, nullptr, nullptr, (float*)d_out);
}

// Round 7
// 128.521 us; speedup vs baseline: 1.5063x; 1.0125x over previous
//
#include <hip/hip_runtime.h>
#include <hip/hip_bf16.h>

#define NHEADS 12
#define NFRAMES 8
#define NTOK 1568
#define CDIM 768
#define DHEAD 64
#define BATCH 2
#define MROWS (BATCH * NTOK) /* 3136 */
#define MPAD 3200
#define K3 (3 * CDIM)        /* 2304 */
#define AREA1 197
#define EXT1 228
#define TPF 196
#define LOG2E 1.4426950408889634f

typedef __bf16 bf16x8 __attribute__((ext_vector_type(8)));
typedef float f32x4 __attribute__((ext_vector_type(4)));
typedef float f32x16 __attribute__((ext_vector_type(16)));
typedef unsigned short u16x8 __attribute__((ext_vector_type(8)));

#if __has_builtin(__builtin_amdgcn_exp2f)
#define EXP2(x) __builtin_amdgcn_exp2f(x)
#else
#define EXP2(x) exp2f(x)
#endif

__device__ __forceinline__ unsigned short f2bf(float f) {
  return __builtin_bit_cast(unsigned short, (__bf16)f);
}
__device__ __forceinline__ float bf2f(unsigned short u) {
  unsigned int x = ((unsigned int)u) << 16;
  return __builtin_bit_cast(float, x);
}
__device__ __forceinline__ bf16x8 ld8(const unsigned short* p) {
  return __builtin_bit_cast(bf16x8, *(const u16x8*)p);
}
__device__ __forceinline__ f32x4 mfma16(bf16x8 a, bf16x8 b, f32x4 c) {
  return __builtin_amdgcn_mfma_f32_16x16x32_bf16(a, b, c, 0, 0, 0);
}
__device__ __forceinline__ f32x16 mfma32(bf16x8 a, bf16x8 b, f32x16 c) {
  return __builtin_amdgcn_mfma_f32_32x32x16_bf16(a, b, c, 0, 0, 0);
}
__device__ __forceinline__ unsigned int pack2(float lo, float hi) {
  return ((unsigned int)f2bf(hi) << 16) | (unsigned int)f2bf(lo);
}
// x = {a_lo, b_lo}, y = {a_hi, b_hi} across the lane<32 / lane>=32 halves.
__device__ __forceinline__ void swap32(unsigned int a, unsigned int b,
                                       unsigned int& x, unsigned int& y) {
#if __has_builtin(__builtin_amdgcn_permlane32_swap)
  auto r = __builtin_amdgcn_permlane32_swap(a, b, false, false);
  x = r[0]; y = r[1];
#else
  const bool hi = (threadIdx.x & 63) >= 32;
  unsigned int ea = (unsigned int)__shfl_xor((int)a, 32);
  unsigned int eb = (unsigned int)__shfl_xor((int)b, 32);
  x = hi ? eb : a;
  y = hi ? b : ea;
#endif
}

// ---------------- conversion / packing ----------------
__global__ void conv_kernel(const float* __restrict__ x,
                            const float* __restrict__ qkv_w,
                            const float* __restrict__ proj_w,
                            unsigned short* __restrict__ xb,
                            unsigned short* __restrict__ qkvwb,
                            unsigned short* __restrict__ projwb,
                            unsigned short* __restrict__ aout) {
  const int XCH = MPAD * CDIM / 4;
  const int WCH = K3 * CDIM / 4;
  const int PCH = CDIM * CDIM / 4;
  const int ACH = (MPAD - MROWS) * CDIM / 4;
  const int total = XCH + WCH + PCH + ACH;
  for (int c = blockIdx.x * blockDim.x + threadIdx.x; c < total;
       c += gridDim.x * blockDim.x) {
    if (c < XCH) {
      int m = (c * 4) / CDIM;
      float4 v = make_float4(0.f, 0.f, 0.f, 0.f);
      if (m < MROWS) v = ((const float4*)x)[c];
      ushort4 o;
      o.x = f2bf(v.x); o.y = f2bf(v.y); o.z = f2bf(v.z); o.w = f2bf(v.w);
      ((ushort4*)xb)[c] = o;
    } else if (c < XCH + WCH) {
      int c2 = c - XCH;
      float4 v = ((const float4*)qkv_w)[c2];
      ushort4 o;
      o.x = f2bf(v.x); o.y = f2bf(v.y); o.z = f2bf(v.z); o.w = f2bf(v.w);
      ((ushort4*)qkvwb)[c2] = o;
    } else if (c < XCH + WCH + PCH) {
      int c2 = c - XCH - WCH;
      float4 v = ((const float4*)proj_w)[c2];
      ushort4 o;
      o.x = f2bf(v.x); o.y = f2bf(v.y); o.z = f2bf(v.z); o.w = f2bf(v.w);
      ((ushort4*)projwb)[c2] = o;
    } else {
      int c2 = c - XCH - WCH - PCH;
      ushort4 z; z.x = 0; z.y = 0; z.z = 0; z.w = 0;
      ((ushort4*)(aout + (size_t)MROWS * CDIM))[c2] = z;
    }
  }
}

// ---------------- bias table pre-gather ----------------
// bias1Q[h][i=qmod<197][j=km_ext<228] (bf16, pre-scaled by log2e): per-lane row
// layout -> 16 imm-offset loads per attn tile.  bias2[h][qframe][kframe] (f32, xlog2e).
__global__ void bias_kernel(const float* __restrict__ rpt,
                            const float* __restrict__ rtt,
                            const int* __restrict__ rpi,
                            const int* __restrict__ rti,
                            unsigned short* __restrict__ bias1Q,
                            float* __restrict__ bias2) {
  int t = blockIdx.x * blockDim.x + threadIdx.x;
  const int n1 = NHEADS * AREA1 * EXT1;
  if (t < n1) {
    int h = t / (AREA1 * EXT1);
    int rem = t - h * (AREA1 * EXT1);
    int i = rem / EXT1;                 // qmod
    int j = rem - i * EXT1;             // km extended
    int jm = (j >= AREA1) ? j - AREA1 : j;
    bias1Q[t] = f2bf(rpt[rpi[i * AREA1 + jm] * NHEADS + h] * LOG2E);
  } else if (t < n1 + NHEADS * 64) {
    int t2 = t - n1;
    int h = t2 >> 6, ff = t2 & 63;
    bias2[t2] = rtt[rti[ff] * NHEADS + h] * LOG2E;
  }
}

// ---------------- BM x BN MFMA GEMM (NT: both A,B row-major over K) ----------------
template <int MODE, int BM, int BN>
__global__ __launch_bounds__(256) void gemm_kernel(
    const unsigned short* __restrict__ A,
    const unsigned short* __restrict__ Bw,
    const float* __restrict__ bias0,   // q_bias (MODE0) / proj_b (MODE1)
    const float* __restrict__ biasv,   // v_bias (MODE0)
    unsigned short* __restrict__ qbuf,
    unsigned short* __restrict__ kbuf,
    unsigned short* __restrict__ vtbuf,
    float* __restrict__ Cout) {
  __shared__ unsigned short As[2][BM * 32];
  __shared__ unsigned short Bs[2][BN * 32];
  const int lane = threadIdx.x & 63;
  const int wv = threadIdx.x >> 6;
  const int tid = threadIdx.x;
  const int m0 = blockIdx.y * BM;
  const int n0 = blockIdx.x * BN;
  constexpr int WM = BM / 2, WN = BN / 2;

  auto stage = [&](int buf, int kt) {
    const int k0 = kt * 32;
#pragma unroll
    for (int ai = 0; ai < BM / 64; ++ai) {
      const int c = ai * 256 + tid;
      const int r = c >> 2, seg = c & 3;
      __builtin_amdgcn_global_load_lds(
          (const __attribute__((address_space(1))) void*)(A + (size_t)(m0 + r) * CDIM + k0 + seg * 8),
          (__attribute__((address_space(3))) void*)&As[buf][c * 8], 16, 0, 0);
    }
#pragma unroll
    for (int bi = 0; bi < BN / 64; ++bi) {
      const int c = bi * 256 + tid;
      const int r = c >> 2, seg = c & 3;
      __builtin_amdgcn_global_load_lds(
          (const __attribute__((address_space(1))) void*)(Bw + (size_t)(n0 + r) * CDIM + k0 + seg * 8),
          (__attribute__((address_space(3))) void*)&Bs[buf][c * 8], 16, 0, 0);
    }
  };

  f32x4 acc[WM / 16][WN / 16] = {};
  const int rbase = (wv >> 1) * WM;
  const int cbase = (wv & 1) * WN;

  stage(0, 0);
  __syncthreads();
  int cur = 0;
  for (int kt = 0; kt < CDIM / 32; ++kt) {
    if (kt + 1 < CDIM / 32) stage(cur ^ 1, kt + 1);
    bf16x8 af[WM / 16], bg[WN / 16];
#pragma unroll
    for (int i = 0; i < WM / 16; ++i)
      af[i] = ld8(&As[cur][(rbase + i * 16 + (lane & 15)) * 32 + (lane >> 4) * 8]);
#pragma unroll
    for (int j = 0; j < WN / 16; ++j)
      bg[j] = ld8(&Bs[cur][(cbase + j * 16 + (lane & 15)) * 32 + (lane >> 4) * 8]);
#pragma unroll
    for (int i = 0; i < WM / 16; ++i)
#pragma unroll
      for (int j = 0; j < WN / 16; ++j)
        acc[i][j] = mfma16(af[i], bg[j], acc[i][j]);
    __syncthreads();
    cur ^= 1;
  }

#pragma unroll
  for (int i = 0; i < WM / 16; ++i) {
#pragma unroll
    for (int j = 0; j < WN / 16; ++j) {
#pragma unroll
      for (int r = 0; r < 4; ++r) {
        int grow = m0 + rbase + i * 16 + (lane >> 4) * 4 + r;
        int gcol = n0 + cbase + j * 16 + (lane & 15);
        if (grow >= MROWS) continue;
        float v = acc[i][j][r];
        if (MODE == 0) {
          int which = gcol / CDIM;
          int cc = gcol - which * CDIM;
          int hh = cc >> 6, dd = cc & 63;
          int b = grow / NTOK, n = grow - b * NTOK;
          size_t hd = ((size_t)(b * NHEADS + hh) * NTOK + n) * 64 + dd;
          if (which == 0)
            qbuf[hd] = f2bf((v + bias0[cc]) * (0.125f * LOG2E));  // exp2-domain fold
          else if (which == 1)
            kbuf[hd] = f2bf(v);
          else
            vtbuf[((size_t)(b * NHEADS + hh) * 64 + dd) * NTOK + n] =
                f2bf(v + biasv[cc]);
        } else {
          Cout[(size_t)grow * CDIM + gcol] = v + bias0[gcol];
        }
      }
    }
  }
}

// ---------------- flash attention v7: V prefetch + permlane exchange ----------------
// 1176 blocks (one per bh x q-tile), 4 waves each own k-tiles kt = wv, wv+4, ...
// XCD-swizzled blockIdx (1176 = 8*147). Two-phase LDS merge.
// R7: (1) V prefetched one full tile ahead (was issued ~150cy before use; the
// 64-line scattered L2/L3 read is 400-900cy -> naked stall each tile);
// (2) P cross-half exchange via 4 permlane32_swap (VALU) replacing 8 shfl_xor
// (LDS pipe, on the serial softmax chain) + 8 cndmask; (3) cross-half max/sum
// reductions via permlane32_swap; (4) max3-fusable reduction tree.
__global__ __launch_bounds__(256) void attn_kernel(
    const unsigned short* __restrict__ qbuf,
    const unsigned short* __restrict__ kbuf,
    const unsigned short* __restrict__ vtbuf,
    const unsigned short* __restrict__ bias1Q,
    const float* __restrict__ bias2,
    unsigned short* __restrict__ aout) {
  __shared__ float olds[4][64][19];
  const int lane = threadIdx.x & 63;
  const int wv = threadIdx.x >> 6;
  const int wu = (blockIdx.x & 7) * 147 + (blockIdx.x >> 3);  // 0..1175
  const int bh = wu / 49;
  const int qt = wu - bh * 49;
  const int q0 = qt * 32;
  const int h = bh % NHEADS;
  const int b = bh / NHEADS;
  const int qlane = lane & 31;
  const int hi = lane >> 5;
  const int hi4 = hi * 4;
  const int qn = q0 + qlane;
  const int qfr = qn / TPF;
  const int qmod = qn % AREA1;

  const unsigned short* qp = qbuf + (size_t)bh * NTOK * DHEAD;
  const unsigned short* kp = kbuf + (size_t)bh * NTOK * DHEAD;
  const unsigned short* vp = vtbuf + (size_t)bh * DHEAD * NTOK;
  const unsigned short* bq = bias1Q + ((size_t)h * AREA1 + qmod) * EXT1 + hi4;
  const float* b2q = bias2 + h * 64 + qfr * 8;

  bf16x8 aq[4];
#pragma unroll
  for (int c = 0; c < 4; ++c)
    aq[c] = ld8(qp + (size_t)qn * DHEAD + c * 16 + hi * 8);

  f32x16 o0 = {}, o1 = {};
  float mrun = -1.0e30f, lrun = 0.f;

  // tile-0 state: K frags, V frags, bias row chunk, b2 scalars
  bf16x8 kf[4], vf[4];
#pragma unroll
  for (int c = 0; c < 4; ++c)
    kf[c] = ld8(kp + (size_t)(wv * 32 + qlane) * DHEAD + c * 16 + hi * 8);
  {
    const int kv0 = wv * 32;
    vf[0] = ld8(vp + (size_t)qlane * NTOK + kv0 + hi * 8);
    vf[1] = ld8(vp + (size_t)qlane * NTOK + kv0 + 16 + hi * 8);
    vf[2] = ld8(vp + (size_t)(32 + qlane) * NTOK + kv0 + hi * 8);
    vf[3] = ld8(vp + (size_t)(32 + qlane) * NTOK + kv0 + 16 + hi * 8);
  }
  unsigned short ub[16];
  float b2lo, b2hi;
  int base = wv * 32;  // kv0 % 197
  int kfl = (wv * 32) / TPF;
  {
    const unsigned short* bp = bq + base;
#pragma unroll
    for (int r = 0; r < 16; ++r) ub[r] = bp[(r & 3) + 8 * (r >> 2)];
    b2lo = b2q[kfl];
    b2hi = b2q[kfl < 7 ? kfl + 1 : 7];
  }

  for (int kt = wv; kt < NTOK / 32; kt += 4) {
    const int kv0 = kt * 32;
    // C-init = bias1 (log2e domain); QK^T accumulates on top
    f32x16 s;
#pragma unroll
    for (int r = 0; r < 16; ++r) s[r] = bf2f(ub[r]);
    __builtin_amdgcn_s_setprio(1);
#pragma unroll
    for (int c = 0; c < 4; ++c) s = mfma32(kf[c], aq[c], s);
    __builtin_amdgcn_s_setprio(0);

    // prefetch next tile's K, bias1 row chunk, b2 scalars
    int basen = base + 128; if (basen >= AREA1) basen -= AREA1;
    int kfln = kfl;
    float nb2lo = 0.f, nb2hi = 0.f;
    const bool more = (kt + 4 < NTOK / 32);
    if (more) {
#pragma unroll
      for (int c = 0; c < 4; ++c)
        kf[c] = ld8(kp + (size_t)(kv0 + 128 + qlane) * DHEAD + c * 16 + hi * 8);
      const unsigned short* bp = bq + basen;
#pragma unroll
      for (int r = 0; r < 16; ++r) ub[r] = bp[(r & 3) + 8 * (r >> 2)];
      kfln = (kv0 + 128) / TPF;
      nb2lo = b2q[kfln];
      nb2hi = b2q[kfln < 7 ? kfln + 1 : 7];
    }

    // bias2: uniform per tile unless the tile crosses a frame boundary
    const int ccr = (kfl + 1) * TPF - kv0;  // in (0, 196]
    if (ccr < 32) {
      const float dlt = b2hi - b2lo;
#pragma unroll
      for (int r = 0; r < 16; ++r)
        s[r] += ((r & 3) + 8 * (r >> 2) + hi4 >= ccr) ? dlt : 0.f;
    }

    // max3-fusable tree over 16 regs + permlane cross-half
    float a0 = fmaxf(fmaxf(s[0], s[1]), s[2]);
    float a1 = fmaxf(fmaxf(s[3], s[4]), s[5]);
    float a2 = fmaxf(fmaxf(s[6], s[7]), s[8]);
    float a3 = fmaxf(fmaxf(s[9], s[10]), s[11]);
    float a4 = fmaxf(fmaxf(s[12], s[13]), s[14]);
    float tmax = fmaxf(fmaxf(fmaxf(a0, a1), a2), fmaxf(fmaxf(a3, a4), s[15]));
    {
      unsigned int tx, ty;
      swap32(__builtin_bit_cast(unsigned int, tmax),
             __builtin_bit_cast(unsigned int, tmax), tx, ty);
      tmax = fmaxf(__builtin_bit_cast(float, tx), __builtin_bit_cast(float, ty));
    }
    const float tb = tmax + b2lo;
    if (!__all(tb - mrun <= 11.5f)) {  // T13 defer-max (log2 domain)
      const float mnew = fmaxf(mrun, tb);
      const float fac = EXP2(mrun - mnew);
      lrun *= fac;
#pragma unroll
      for (int r = 0; r < 16; ++r) { o0[r] *= fac; o1[r] *= fac; }
      mrun = mnew;
    }
    const float mm = mrun - b2lo;  // fold uniform bias2 into subtrahend
#pragma unroll
    for (int r = 0; r < 16; ++r) s[r] = EXP2(s[r] - mm);
    float s0a = (s[0] + s[1]) + (s[2] + s[3]);
    float s1a = (s[4] + s[5]) + (s[6] + s[7]);
    float s2a = (s[8] + s[9]) + (s[10] + s[11]);
    float s3a = (s[12] + s[13]) + (s[14] + s[15]);
    float ps = (s0a + s1a) + (s2a + s3a);
    {
      unsigned int px, py;
      swap32(__builtin_bit_cast(unsigned int, ps),
             __builtin_bit_cast(unsigned int, ps), px, py);
      ps = __builtin_bit_cast(float, px) + __builtin_bit_cast(float, py);
    }
    lrun += ps;

    // pack P -> bf16 pairs; exchange halves via permlane32_swap
    unsigned int dw[8];
#pragma unroll
    for (int c = 0; c < 8; ++c) dw[c] = pack2(s[2 * c], s[2 * c + 1]);
    unsigned int f0[4], f1[4];
    swap32(dw[0], dw[2], f0[0], f0[2]);
    swap32(dw[1], dw[3], f0[1], f0[3]);
    swap32(dw[4], dw[6], f1[0], f1[2]);
    swap32(dw[5], dw[7], f1[1], f1[3]);
    const bf16x8 F0 = __builtin_bit_cast(bf16x8, *(ulonglong2*)f0);
    const bf16x8 F1 = __builtin_bit_cast(bf16x8, *(ulonglong2*)f1);

    __builtin_amdgcn_s_setprio(1);
    o0 = mfma32(vf[0], F0, o0);
    o0 = mfma32(vf[1], F1, o0);
    o1 = mfma32(vf[2], F0, o1);
    o1 = mfma32(vf[3], F1, o1);
    __builtin_amdgcn_s_setprio(0);

    // V prefetch for next tile (after PV consumes current vf)
    if (more) {
      vf[0] = ld8(vp + (size_t)qlane * NTOK + kv0 + 128 + hi * 8);
      vf[1] = ld8(vp + (size_t)qlane * NTOK + kv0 + 144 + hi * 8);
      vf[2] = ld8(vp + (size_t)(32 + qlane) * NTOK + kv0 + 128 + hi * 8);
      vf[3] = ld8(vp + (size_t)(32 + qlane) * NTOK + kv0 + 144 + hi * 8);
    }

    base = basen;
    kfl = kfln;
    b2lo = nb2lo;
    b2hi = nb2hi;
  }

  // ---- two-phase merge: phase A = o0 (+m,l), phase B = o1 (reuses buffer) ----
  float* row = &olds[wv][lane][0];
#pragma unroll
  for (int r = 0; r < 16; ++r) row[r] = o0[r];
  row[16] = mrun;
  row[17] = lrun;
  __syncthreads();

  float wgt[4], L = 0.f, M = -1.0e30f;
#pragma unroll
  for (int s4 = 0; s4 < 4; ++s4) M = fmaxf(M, olds[s4][lane][16]);
#pragma unroll
  for (int s4 = 0; s4 < 4; ++s4) {
    wgt[s4] = EXP2(olds[s4][lane][16] - M);
    L += olds[s4][lane][17] * wgt[s4];
  }
  const float rinv = 1.0f / L;
  unsigned short* op = aout + (size_t)(b * NTOK + qn) * CDIM + h * 64;
  const int dbase = 8 * wv + 4 * hi;
  {
    float acc[4] = {0.f, 0.f, 0.f, 0.f};
#pragma unroll
    for (int s4 = 0; s4 < 4; ++s4)
#pragma unroll
      for (int j = 0; j < 4; ++j)
        acc[j] += olds[s4][lane][4 * wv + j] * wgt[s4];
    *(unsigned int*)(op + dbase) = pack2(acc[0] * rinv, acc[1] * rinv);
    *(unsigned int*)(op + dbase + 2) = pack2(acc[2] * rinv, acc[3] * rinv);
  }
  __syncthreads();
#pragma unroll
  for (int r = 0; r < 16; ++r) row[r] = o1[r];
  __syncthreads();
  {
    float acc[4] = {0.f, 0.f, 0.f, 0.f};
#pragma unroll
    for (int s4 = 0; s4 < 4; ++s4)
#pragma unroll
      for (int j = 0; j < 4; ++j)
        acc[j] += olds[s4][lane][4 * wv + j] * wgt[s4];
    *(unsigned int*)(op + 32 + dbase) = pack2(acc[0] * rinv, acc[1] * rinv);
    *(unsigned int*)(op + 32 + dbase + 2) = pack2(acc[2] * rinv, acc[3] * rinv);
  }
}

extern "C" void kernel_launch(void* const* d_in, const int* in_sizes, int n_in,
                              void* d_out, int out_size, void* d_ws, size_t ws_size,
                              hipStream_t stream) {
  (void)in_sizes; (void)n_in; (void)out_size; (void)ws_size;
  const float* x        = (const float*)d_in[0];
  const float* qkv_w    = (const float*)d_in[1];
  const float* q_bias   = (const float*)d_in[2];
  const float* v_bias   = (const float*)d_in[3];
  const float* rp_table = (const float*)d_in[4];
  const float* rt_table = (const float*)d_in[5];
  const float* proj_w   = (const float*)d_in[6];
  const float* proj_b   = (const float*)d_in[7];
  const int* rp_index   = (const int*)d_in[8];
  const int* rt_index   = (const int*)d_in[9];

  char* ws = (char*)d_ws;
  unsigned short* xb     = (unsigned short*)(ws);
  unsigned short* qkvwb  = (unsigned short*)(ws + 4915200);
  unsigned short* projwb = (unsigned short*)(ws + 8454144);
  unsigned short* qbuf   = (unsigned short*)(ws + 9633792);
  unsigned short* kbuf   = (unsigned short*)(ws + 14450688);
  unsigned short* vtbuf  = (unsigned short*)(ws + 19267584);
  unsigned short* aout   = (unsigned short*)(ws + 24084480);
  unsigned short* bias1Q = (unsigned short*)(ws + 28999680);  // 12*197*228*2 = 1,078,224 B
  float* bias2           = (float*)(ws + 30247424);

  conv_kernel<<<2048, 256, 0, stream>>>(x, qkv_w, proj_w, xb, qkvwb, projwb, aout);
  bias_kernel<<<(NHEADS * AREA1 * EXT1 + NHEADS * 64 + 255) / 256, 256, 0, stream>>>(
      rp_table, rt_table, rp_index, rt_index, bias1Q, bias2);
  gemm_kernel<0, 128, 64><<<dim3(K3 / 64, MPAD / 128), 256, 0, stream>>>(
      xb, qkvwb, q_bias, v_bias, qbuf, kbuf, vtbuf, nullptr);
  attn_kernel<<<dim3(1176), 256, 0, stream>>>(
      qbuf, kbuf, vtbuf, bias1Q, bias2, aout);
  gemm_kernel<1, 64, 64><<<dim3(CDIM / 64, MPAD / 64), 256, 0, stream>>>(
      aout, projwb, proj_b, nullptr, nullptr, nullptr, nullptr, (float*)d_out);
}